// Round 1
// baseline (69008.203 us; speedup 1.0000x reference)
//
#include <hip/hip_runtime.h>
#include <math.h>

#define BB 8
#define NN 2048
#define KNB 20

// ---------------------------------------------------------------- kernels

__global__ void sq_kernel(const float* __restrict__ x, int bs, int C,
                          float* __restrict__ sq) {
  int t = blockIdx.x * blockDim.x + threadIdx.x;
  int b = t / NN, n = t % NN;
  const float* xp = x + b * bs + n;
  float s = 0.f;
  for (int c = 0; c < C; ++c) { float v = xp[c * NN]; s += v * v; }
  sq[t] = s;
}

// one thread per (b,n): scan all m, keep top-20 largest pd (= -dist^2), self skipped
__global__ void knn_kernel(const float* __restrict__ x, int bs, int C,
                           const float* __restrict__ sq, int* __restrict__ idx) {
  int t = blockIdx.x * blockDim.x + threadIdx.x;
  int b = t / NN, n = t % NN;
  const float* xb = x + b * bs;
  const float* xn = xb + n;
  float sqn = sq[b * NN + n];
  float best[KNB]; int bidx[KNB];
#pragma unroll
  for (int i = 0; i < KNB; ++i) { best[i] = -INFINITY; bidx[i] = 0; }
  for (int m = 0; m < NN; ++m) {
    if (m == n) continue;
    const float* xm = xb + m;
    float dot = 0.f;
    for (int c = 0; c < C; ++c) dot += xn[c * NN] * xm[c * NN];
    float pd = 2.f * dot - sqn - sq[b * NN + m];
    if (pd > best[KNB - 1]) {
      int j = KNB - 1;
      while (j > 0 && best[j - 1] < pd) {
        best[j] = best[j - 1]; bidx[j] = bidx[j - 1]; --j;
      }
      best[j] = pd; bidx[j] = m;
    }
  }
  int* op = idx + (b * NN + n) * KNB;
#pragma unroll
  for (int i = 0; i < KNB; ++i) op[i] = bidx[i];
}

// one block (128 thr) per point. out = wv @ (sum_k softmax_k * nb_k - f)
// att written in [B,C,N] layout.
__global__ void att_kernel(const float* __restrict__ x, int bs, int C,
                           const int* __restrict__ idx,
                           const float* __restrict__ wq, const float* __restrict__ wk,
                           const float* __restrict__ wv, float* __restrict__ att) {
  int n = blockIdx.x % NN;
  int b = blockIdx.x / NN;
  int tid = threadIdx.x;
  __shared__ float f[128], q[128], qk[128], agg[128];
  __shared__ float s[KNB];
  __shared__ float nb[KNB][129];
  __shared__ int nidx[KNB];
  const float* xb = x + b * bs;
  for (int c = tid; c < C; c += 128) f[c] = xb[c * NN + n];
  if (tid < KNB) nidx[tid] = idx[(b * NN + n) * KNB + tid];
  __syncthreads();
  for (int kc = tid; kc < KNB * C; kc += 128) {
    int k = kc / C, c = kc - k * C;
    nb[k][c] = xb[c * NN + nidx[k]];
  }
  __syncthreads();
  if (tid < C) {
    float a = 0.f;
    for (int c = 0; c < C; ++c) a += f[c] * wq[tid * C + c];
    q[tid] = a;
  }
  __syncthreads();
  if (tid < C) {
    float a = 0.f;
    for (int e = 0; e < C; ++e) a += q[e] * wk[e * C + tid];
    qk[tid] = a;
  }
  __syncthreads();
  if (tid < KNB) {
    float a = 0.f;
    for (int c = 0; c < C; ++c) a += nb[tid][c] * qk[c];
    s[tid] = a / sqrtf((float)C);
  }
  __syncthreads();
  if (tid == 0) {
    float mx = -INFINITY;
    for (int k = 0; k < KNB; ++k) mx = fmaxf(mx, s[k]);
    float sum = 0.f;
    for (int k = 0; k < KNB; ++k) { s[k] = expf(s[k] - mx); sum += s[k]; }
    float inv = 1.f / sum;
    for (int k = 0; k < KNB; ++k) s[k] *= inv;
  }
  __syncthreads();
  if (tid < C) {
    float a = 0.f;
    for (int k = 0; k < KNB; ++k) a += s[k] * nb[k][tid];
    agg[tid] = a - f[tid];
  }
  __syncthreads();
  if (tid < C) {
    float a = 0.f;
    for (int c = 0; c < C; ++c) a += wv[tid * C + c] * agg[c];
    att[(b * C + tid) * NN + n] = a;
  }
}

// z[b,o,n] = sum_c w[o,c] * in[b,c,n]; each thread does TO consecutive o's
template <int TO>
__global__ void conv_kernel(const float* __restrict__ in, int inBS, int C,
                            const float* __restrict__ w, float* __restrict__ z, int O) {
  int n = blockIdx.x * blockDim.x + threadIdx.x;
  int o0 = blockIdx.y * TO;
  int b = blockIdx.z;
  const float* ip = in + b * inBS + n;
  const float* wp = w + o0 * C;
  float acc[TO];
#pragma unroll
  for (int j = 0; j < TO; ++j) acc[j] = 0.f;
  for (int c = 0; c < C; ++c) {
    float v = ip[c * NN];
#pragma unroll
    for (int j = 0; j < TO; ++j) acc[j] += v * wp[j * C + c];
  }
#pragma unroll
  for (int j = 0; j < TO; ++j) z[(b * O + o0 + j) * NN + n] = acc[j];
}

__global__ void bn_stats_kernel(const float* __restrict__ z, int O,
                                float* __restrict__ mean, float* __restrict__ rstd) {
  int o = blockIdx.x;
  __shared__ float s1[256], s2[256];
  float a1 = 0.f, a2 = 0.f;
  for (int i = threadIdx.x; i < BB * NN; i += 256) {
    int b = i / NN, n = i % NN;
    float v = z[(b * O + o) * NN + n];
    a1 += v; a2 += v * v;
  }
  s1[threadIdx.x] = a1; s2[threadIdx.x] = a2;
  __syncthreads();
  for (int st = 128; st > 0; st >>= 1) {
    if (threadIdx.x < st) {
      s1[threadIdx.x] += s1[threadIdx.x + st];
      s2[threadIdx.x] += s2[threadIdx.x + st];
    }
    __syncthreads();
  }
  if (threadIdx.x == 0) {
    float m = s1[0] / (BB * NN);
    float var = s2[0] / (BB * NN) - m * m;
    mean[o] = m;
    rstd[o] = rsqrtf(var + 1e-5f);
  }
}

__global__ void bn_apply_kernel(const float* __restrict__ z, int O,
                                const float* __restrict__ mean, const float* __restrict__ rstd,
                                float* __restrict__ out, int outBS, int c0) {
  int n = blockIdx.x * blockDim.x + threadIdx.x;
  int o = blockIdx.y, b = blockIdx.z;
  float v = (z[(b * O + o) * NN + n] - mean[o]) * rstd[o];
  out[b * outBS + (c0 + o) * NN + n] = v >= 0.f ? v : 0.2f * v;
}

__global__ void copy_kernel(const float* __restrict__ x, int bs,
                            float* __restrict__ out, int outBS, int c0) {
  int n = blockIdx.x * blockDim.x + threadIdx.x;
  int c = blockIdx.y, b = blockIdx.z;
  out[b * outBS + (c0 + c) * NN + n] = x[b * bs + c * NN + n];
}

__global__ void pool_kernel(const float* __restrict__ z, float* __restrict__ p) {
  int o = blockIdx.x, b = blockIdx.y;
  const float* zp = z + (b * 1024 + o) * NN;
  __shared__ float smax[256], ssum[256];
  float mx = -INFINITY, sm = 0.f;
  for (int n = threadIdx.x; n < NN; n += 256) {
    float v = zp[n];
    mx = fmaxf(mx, v); sm += v;
  }
  smax[threadIdx.x] = mx; ssum[threadIdx.x] = sm;
  __syncthreads();
  for (int st = 128; st > 0; st >>= 1) {
    if (threadIdx.x < st) {
      smax[threadIdx.x] = fmaxf(smax[threadIdx.x], smax[threadIdx.x + st]);
      ssum[threadIdx.x] += ssum[threadIdx.x + st];
    }
    __syncthreads();
  }
  if (threadIdx.x == 0) {
    p[b * 2048 + o] = smax[0];
    p[b * 2048 + 1024 + o] = ssum[0] * (1.f / NN);
  }
}

__global__ void linear_kernel(const float* __restrict__ in, int IN, int OUT,
                              const float* __restrict__ w, const float* __restrict__ bias,
                              float* __restrict__ out) {
  int t = blockIdx.x * blockDim.x + threadIdx.x;
  if (t >= BB * OUT) return;
  int b = t / OUT, f = t % OUT;
  float a = bias[f];
  const float* ip = in + b * IN;
  const float* wp = w + f * IN;
  for (int i = 0; i < IN; ++i) a += ip[i] * wp[i];
  out[t] = a;
}

__global__ void bnf_kernel(float* __restrict__ t, int F) {
  int f = blockIdx.x * blockDim.x + threadIdx.x;
  if (f >= F) return;
  float s = 0.f, s2 = 0.f;
  for (int b = 0; b < BB; ++b) { float v = t[b * F + f]; s += v; s2 += v * v; }
  float m = s * (1.f / BB);
  float var = s2 * (1.f / BB) - m * m;
  float r = rsqrtf(var + 1e-5f);
  for (int b = 0; b < BB; ++b) {
    float v = (t[b * F + f] - m) * r;
    t[b * F + f] = v >= 0.f ? v : 0.2f * v;
  }
}

// ---------------------------------------------------------------- host side

static inline void run_conv(const float* in, int inBS, int C, int O, const float* w,
                            float* z, hipStream_t st) {
  if (O % 8 == 0)
    conv_kernel<8><<<dim3(NN / 256, O / 8, BB), 256, 0, st>>>(in, inBS, C, w, z, O);
  else  // O == 3
    conv_kernel<3><<<dim3(NN / 256, 1, BB), 256, 0, st>>>(in, inBS, C, w, z, O);
}

struct SAW { const float *wq, *wk, *wv, *wc; };

static inline void run_sa(int C, const float* xin, int xbs, SAW w,
                          float* att, float* z, float* h, float* sq, int* idx,
                          float* mean, float* rstd, hipStream_t st) {
  sq_kernel<<<BB * NN / 256, 256, 0, st>>>(xin, xbs, C, sq);
  knn_kernel<<<BB * NN / 64, 64, 0, st>>>(xin, xbs, C, sq, idx);
  att_kernel<<<BB * NN, 128, 0, st>>>(xin, xbs, C, idx, w.wq, w.wk, w.wv, att);
  run_conv(att, C * NN, C, C, w.wc, z, st);
  bn_stats_kernel<<<C, 256, 0, st>>>(z, C, mean, rstd);
  bn_apply_kernel<<<dim3(NN / 256, C, BB), 256, 0, st>>>(z, C, mean, rstd, h, 2 * C * NN, 0);
  copy_kernel<<<dim3(NN / 256, C, BB), 256, 0, st>>>(xin, xbs, h, 2 * C * NN, C);
}

static inline void run_conv_bn(const float* in, int inBS, int Cin, int O, const float* w,
                               float* z, float* out, int outBS, int c0,
                               float* mean, float* rstd, hipStream_t st) {
  run_conv(in, inBS, Cin, O, w, z, st);
  bn_stats_kernel<<<O, 256, 0, st>>>(z, O, mean, rstd);
  bn_apply_kernel<<<dim3(NN / 256, O, BB), 256, 0, st>>>(z, O, mean, rstd, out, outBS, c0);
}

extern "C" void kernel_launch(void* const* d_in, const int* in_sizes, int n_in,
                              void* d_out, int out_size, void* d_ws, size_t ws_size,
                              hipStream_t stream) {
  const float* x = (const float*)d_in[0];
  SAW sa1{(const float*)d_in[1], (const float*)d_in[2], (const float*)d_in[3], (const float*)d_in[4]};
  SAW sa2{(const float*)d_in[5], (const float*)d_in[6], (const float*)d_in[7], (const float*)d_in[8]};
  SAW sa3{(const float*)d_in[9], (const float*)d_in[10], (const float*)d_in[11], (const float*)d_in[12]};
  SAW sa4{(const float*)d_in[13], (const float*)d_in[14], (const float*)d_in[15], (const float*)d_in[16]};
  const float* conv1_w = (const float*)d_in[17];
  const float* conv2_w = (const float*)d_in[18];
  const float* conv3_w = (const float*)d_in[19];
  const float* conv4_w = (const float*)d_in[20];
  const float* conv5_w = (const float*)d_in[21];
  const float* lin1_w = (const float*)d_in[22];
  const float* lin1_b = (const float*)d_in[23];
  const float* lin2_w = (const float*)d_in[24];
  const float* lin2_b = (const float*)d_in[25];
  const float* lin3_w = (const float*)d_in[26];
  const float* lin3_b = (const float*)d_in[27];

  char* ws = (char*)d_ws;
  size_t off = 0;
  auto take = [&](size_t bytes) -> void* {
    void* p = ws + off;
    off += (bytes + 255) & ~(size_t)255;
    return p;
  };
  float* sq   = (float*)take((size_t)BB * NN * 4);
  int*   idx  = (int*)take((size_t)BB * NN * KNB * 4);
  float* att  = (float*)take((size_t)BB * 128 * NN * 4);
  float* h    = (float*)take((size_t)BB * 256 * NN * 4);
  float* z    = (float*)take((size_t)BB * 1024 * NN * 4);
  float* xc   = (float*)take((size_t)BB * 512 * NN * 4);
  float* mean = (float*)take(1024 * 4);
  float* rstd = (float*)take(1024 * 4);
  float* p    = (float*)take((size_t)BB * 2048 * 4);
  float* t1   = (float*)take((size_t)BB * 512 * 4);
  float* t2   = (float*)take((size_t)BB * 256 * 4);
  (void)ws_size; (void)n_in; (void)in_sizes; (void)out_size;

  // SA1 (C=3) -> h [B,6,N]
  run_sa(3, x, 3 * NN, sa1, att, z, h, sq, idx, mean, rstd, stream);
  // conv1: [B,6,N] -> x1 = xc[:,0:64,:]
  run_conv_bn(h, 6 * NN, 6, 64, conv1_w, z, xc, 512 * NN, 0, mean, rstd, stream);
  // SA2 (C=64) on x1 -> h [B,128,N]
  run_sa(64, xc + 0 * NN, 512 * NN, sa2, att, z, h, sq, idx, mean, rstd, stream);
  // conv2 -> x2 = xc[:,64:128,:]
  run_conv_bn(h, 128 * NN, 128, 64, conv2_w, z, xc, 512 * NN, 64, mean, rstd, stream);
  // SA3 (C=64) on x2 -> h [B,128,N]
  run_sa(64, xc + 64 * NN, 512 * NN, sa3, att, z, h, sq, idx, mean, rstd, stream);
  // conv3 -> x3 = xc[:,128:256,:]
  run_conv_bn(h, 128 * NN, 128, 128, conv3_w, z, xc, 512 * NN, 128, mean, rstd, stream);
  // SA4 (C=128) on x3 -> h [B,256,N]
  run_sa(128, xc + 128 * NN, 512 * NN, sa4, att, z, h, sq, idx, mean, rstd, stream);
  // conv4 -> x4 = xc[:,256:512,:]
  run_conv_bn(h, 256 * NN, 256, 256, conv4_w, z, xc, 512 * NN, 256, mean, rstd, stream);
  // conv5: xc [B,512,N] -> x5 (in place in z) [B,1024,N]
  run_conv_bn(xc, 512 * NN, 512, 1024, conv5_w, z, z, 1024 * NN, 0, mean, rstd, stream);
  // pool -> p [B,2048]
  pool_kernel<<<dim3(1024, BB), 256, 0, stream>>>(z, p);
  // lin1 + bn + lrelu
  linear_kernel<<<(BB * 512 + 255) / 256, 256, 0, stream>>>(p, 2048, 512, lin1_w, lin1_b, t1);
  bnf_kernel<<<2, 256, 0, stream>>>(t1, 512);
  // lin2 + bn + lrelu
  linear_kernel<<<(BB * 256 + 255) / 256, 256, 0, stream>>>(t1, 512, 256, lin2_w, lin2_b, t2);
  bnf_kernel<<<1, 256, 0, stream>>>(t2, 256);
  // lin3 -> out
  linear_kernel<<<(BB * 40 + 255) / 256, 256, 0, stream>>>(t2, 256, 40, lin3_w, lin3_b, (float*)d_out);
}

// Round 2
// 43331.674 us; speedup vs baseline: 1.5926x; 1.5926x over previous
//
#include <hip/hip_runtime.h>
#include <math.h>

#define BB 8
#define NN 2048
#define KNB 20
#define SPLIT 8

// ---------------------------------------------------------------- kernels

__global__ void sq_kernel(const float* __restrict__ x, int bs, int C,
                          float* __restrict__ sq) {
  int t = blockIdx.x * blockDim.x + threadIdx.x;
  int b = t / NN, n = t % NN;
  const float* xp = x + b * bs + n;
  float s = 0.f;
  for (int c = 0; c < C; ++c) { float v = xp[c * NN]; s += v * v; }
  sq[t] = s;
}

// Tiled kNN: block = 256 threads, thread owns one n. m-range = NN/SPLIT per
// block, staged in LDS tiles of TM=32 (read as wave-uniform float4 broadcasts).
// Per-thread top-20 kept in LDS columns (2-way bank alias = free), 20th-best
// cached in a register. Ranking value: 2*dot(xn,xm) - sq[m]  (same order as
// reference pd, which just adds the per-n constant -sq[n]).
template <int C>
__global__ void knn_tile_kernel(const float* __restrict__ x, int bs,
                                const float* __restrict__ sq,
                                float* __restrict__ cand_val,
                                int* __restrict__ cand_idx) {
  constexpr int TM = 32;
  const int tid = threadIdx.x;                 // 0..255
  const int n = blockIdx.x * 256 + tid;        // this thread's point
  const int sp = blockIdx.y;
  const int b = blockIdx.z;
  const int MR = NN / SPLIT;                   // 256 m per block
  const int m0base = sp * MR;

  __shared__ float xm[C * TM];
  __shared__ float sqm[TM];
  __shared__ float bestv[KNB][256];
  __shared__ int besti[KNB][256];

#pragma unroll
  for (int k = 0; k < KNB; ++k) { bestv[k][tid] = -INFINITY; besti[k][tid] = 0; }
  float kmin = -INFINITY;

  const float* xb = x + b * bs;

  for (int t = 0; t < MR / TM; ++t) {
    const int m0 = m0base + t * TM;
    __syncthreads();
    for (int i = tid; i < C * TM; i += 256) {
      int c = i / TM, ml = i % TM;
      xm[i] = xb[c * NN + m0 + ml];
    }
    if (tid < TM) sqm[tid] = sq[b * NN + m0 + tid];
    __syncthreads();

    float acc[TM];
#pragma unroll
    for (int ml = 0; ml < TM; ++ml) acc[ml] = 0.f;

    constexpr int CH = (C / 8) * 8;
#pragma unroll
    for (int c0 = 0; c0 < CH; c0 += 8) {
      float xnr[8];
#pragma unroll
      for (int i = 0; i < 8; ++i) xnr[i] = xb[(c0 + i) * NN + n];
#pragma unroll
      for (int i = 0; i < 8; ++i) {
        const float4* xv = (const float4*)&xm[(c0 + i) * TM];
#pragma unroll
        for (int q = 0; q < TM / 4; ++q) {
          float4 v = xv[q];
          acc[q * 4 + 0] += xnr[i] * v.x;
          acc[q * 4 + 1] += xnr[i] * v.y;
          acc[q * 4 + 2] += xnr[i] * v.z;
          acc[q * 4 + 3] += xnr[i] * v.w;
        }
      }
    }
#pragma unroll
    for (int c = CH; c < C; ++c) {
      float xn1 = xb[c * NN + n];
      const float4* xv = (const float4*)&xm[c * TM];
#pragma unroll
      for (int q = 0; q < TM / 4; ++q) {
        float4 v = xv[q];
        acc[q * 4 + 0] += xn1 * v.x;
        acc[q * 4 + 1] += xn1 * v.y;
        acc[q * 4 + 2] += xn1 * v.z;
        acc[q * 4 + 3] += xn1 * v.w;
      }
    }

    // selection
#pragma unroll
    for (int ml = 0; ml < TM; ++ml) {
      float pdv = 2.f * acc[ml] - sqm[ml];
      int m = m0 + ml;
      if (pdv > kmin && m != n) {
        int j = KNB - 1;
        while (j > 0 && bestv[j - 1][tid] < pdv) {
          bestv[j][tid] = bestv[j - 1][tid];
          besti[j][tid] = besti[j - 1][tid];
          --j;
        }
        bestv[j][tid] = pdv;
        besti[j][tid] = m;
        kmin = bestv[KNB - 1][tid];
      }
    }
  }

  float* cv = cand_val + ((size_t)(b * NN + n) * SPLIT + sp) * KNB;
  int* ci = cand_idx + ((size_t)(b * NN + n) * SPLIT + sp) * KNB;
#pragma unroll
  for (int k = 0; k < KNB; ++k) { cv[k] = bestv[k][tid]; ci[k] = besti[k][tid]; }
}

// merge SPLIT sorted 20-lists per point into final top-20 indices
__global__ void knn_merge_kernel(const float* __restrict__ cand_val,
                                 const int* __restrict__ cand_idx,
                                 int* __restrict__ idx) {
  int t = blockIdx.x * 256 + threadIdx.x;  // b*NN+n
  if (t >= BB * NN) return;
  const float* cv = cand_val + (size_t)t * SPLIT * KNB;
  const int* ci = cand_idx + (size_t)t * SPLIT * KNB;
  int pos[SPLIT];
#pragma unroll
  for (int s = 0; s < SPLIT; ++s) pos[s] = 0;
  int* op = idx + (size_t)t * KNB;
  for (int k = 0; k < KNB; ++k) {
    float best = -INFINITY;
    int bsel = 0, baddr = 0;
#pragma unroll
    for (int s = 0; s < SPLIT; ++s) {
      float v = cv[s * KNB + pos[s]];
      if (v > best) { best = v; bsel = s; baddr = s * KNB + pos[s]; }
    }
    op[k] = ci[baddr];
#pragma unroll
    for (int s = 0; s < SPLIT; ++s)
      if (s == bsel) pos[s]++;
  }
}

// one block (128 thr) per point. out = wv @ (sum_k softmax_k * nb_k - f)
__global__ void att_kernel(const float* __restrict__ x, int bs, int C,
                           const int* __restrict__ idx,
                           const float* __restrict__ wq, const float* __restrict__ wk,
                           const float* __restrict__ wv, float* __restrict__ att) {
  int n = blockIdx.x % NN;
  int b = blockIdx.x / NN;
  int tid = threadIdx.x;
  __shared__ float f[128], q[128], qk[128], agg[128];
  __shared__ float s[KNB];
  __shared__ float nb[KNB][129];
  __shared__ int nidx[KNB];
  const float* xb = x + b * bs;
  for (int c = tid; c < C; c += 128) f[c] = xb[c * NN + n];
  if (tid < KNB) nidx[tid] = idx[(b * NN + n) * KNB + tid];
  __syncthreads();
  for (int kc = tid; kc < KNB * C; kc += 128) {
    int k = kc / C, c = kc - k * C;
    nb[k][c] = xb[c * NN + nidx[k]];
  }
  __syncthreads();
  if (tid < C) {
    float a = 0.f;
    for (int c = 0; c < C; ++c) a += f[c] * wq[tid * C + c];
    q[tid] = a;
  }
  __syncthreads();
  if (tid < C) {
    float a = 0.f;
    for (int e = 0; e < C; ++e) a += q[e] * wk[e * C + tid];
    qk[tid] = a;
  }
  __syncthreads();
  if (tid < KNB) {
    float a = 0.f;
    for (int c = 0; c < C; ++c) a += nb[tid][c] * qk[c];
    s[tid] = a / sqrtf((float)C);
  }
  __syncthreads();
  if (tid == 0) {
    float mx = -INFINITY;
    for (int k = 0; k < KNB; ++k) mx = fmaxf(mx, s[k]);
    float sum = 0.f;
    for (int k = 0; k < KNB; ++k) { s[k] = expf(s[k] - mx); sum += s[k]; }
    float inv = 1.f / sum;
    for (int k = 0; k < KNB; ++k) s[k] *= inv;
  }
  __syncthreads();
  if (tid < C) {
    float a = 0.f;
    for (int k = 0; k < KNB; ++k) a += s[k] * nb[k][tid];
    agg[tid] = a - f[tid];
  }
  __syncthreads();
  if (tid < C) {
    float a = 0.f;
    for (int c = 0; c < C; ++c) a += wv[tid * C + c] * agg[c];
    att[(b * C + tid) * NN + n] = a;
  }
}

// z[b,o,n] = sum_c w[o,c] * in[b,c,n]; each thread does TO consecutive o's
template <int TO>
__global__ void conv_kernel(const float* __restrict__ in, int inBS, int C,
                            const float* __restrict__ w, float* __restrict__ z, int O) {
  int n = blockIdx.x * blockDim.x + threadIdx.x;
  int o0 = blockIdx.y * TO;
  int b = blockIdx.z;
  const float* ip = in + b * inBS + n;
  const float* wp = w + o0 * C;
  float acc[TO];
#pragma unroll
  for (int j = 0; j < TO; ++j) acc[j] = 0.f;
  for (int c = 0; c < C; ++c) {
    float v = ip[c * NN];
#pragma unroll
    for (int j = 0; j < TO; ++j) acc[j] += v * wp[j * C + c];
  }
#pragma unroll
  for (int j = 0; j < TO; ++j) z[(b * O + o0 + j) * NN + n] = acc[j];
}

__global__ void bn_stats_kernel(const float* __restrict__ z, int O,
                                float* __restrict__ mean, float* __restrict__ rstd) {
  int o = blockIdx.x;
  __shared__ float s1[256], s2[256];
  float a1 = 0.f, a2 = 0.f;
  for (int i = threadIdx.x; i < BB * NN; i += 256) {
    int b = i / NN, n = i % NN;
    float v = z[(b * O + o) * NN + n];
    a1 += v; a2 += v * v;
  }
  s1[threadIdx.x] = a1; s2[threadIdx.x] = a2;
  __syncthreads();
  for (int st = 128; st > 0; st >>= 1) {
    if (threadIdx.x < st) {
      s1[threadIdx.x] += s1[threadIdx.x + st];
      s2[threadIdx.x] += s2[threadIdx.x + st];
    }
    __syncthreads();
  }
  if (threadIdx.x == 0) {
    float m = s1[0] / (BB * NN);
    float var = s2[0] / (BB * NN) - m * m;
    mean[o] = m;
    rstd[o] = rsqrtf(var + 1e-5f);
  }
}

__global__ void bn_apply_kernel(const float* __restrict__ z, int O,
                                const float* __restrict__ mean, const float* __restrict__ rstd,
                                float* __restrict__ out, int outBS, int c0) {
  int n = blockIdx.x * blockDim.x + threadIdx.x;
  int o = blockIdx.y, b = blockIdx.z;
  float v = (z[(b * O + o) * NN + n] - mean[o]) * rstd[o];
  out[b * outBS + (c0 + o) * NN + n] = v >= 0.f ? v : 0.2f * v;
}

__global__ void copy_kernel(const float* __restrict__ x, int bs,
                            float* __restrict__ out, int outBS, int c0) {
  int n = blockIdx.x * blockDim.x + threadIdx.x;
  int c = blockIdx.y, b = blockIdx.z;
  out[b * outBS + (c0 + c) * NN + n] = x[b * bs + c * NN + n];
}

__global__ void pool_kernel(const float* __restrict__ z, float* __restrict__ p) {
  int o = blockIdx.x, b = blockIdx.y;
  const float* zp = z + (b * 1024 + o) * NN;
  __shared__ float smax[256], ssum[256];
  float mx = -INFINITY, sm = 0.f;
  for (int n = threadIdx.x; n < NN; n += 256) {
    float v = zp[n];
    mx = fmaxf(mx, v); sm += v;
  }
  smax[threadIdx.x] = mx; ssum[threadIdx.x] = sm;
  __syncthreads();
  for (int st = 128; st > 0; st >>= 1) {
    if (threadIdx.x < st) {
      smax[threadIdx.x] = fmaxf(smax[threadIdx.x], smax[threadIdx.x + st]);
      ssum[threadIdx.x] += ssum[threadIdx.x + st];
    }
    __syncthreads();
  }
  if (threadIdx.x == 0) {
    p[b * 2048 + o] = smax[0];
    p[b * 2048 + 1024 + o] = ssum[0] * (1.f / NN);
  }
}

__global__ void linear_kernel(const float* __restrict__ in, int IN, int OUT,
                              const float* __restrict__ w, const float* __restrict__ bias,
                              float* __restrict__ out) {
  int t = blockIdx.x * blockDim.x + threadIdx.x;
  if (t >= BB * OUT) return;
  int b = t / OUT, f = t % OUT;
  float a = bias[f];
  const float* ip = in + b * IN;
  const float* wp = w + f * IN;
  for (int i = 0; i < IN; ++i) a += ip[i] * wp[i];
  out[t] = a;
}

__global__ void bnf_kernel(float* __restrict__ t, int F) {
  int f = blockIdx.x * blockDim.x + threadIdx.x;
  if (f >= F) return;
  float s = 0.f, s2 = 0.f;
  for (int b = 0; b < BB; ++b) { float v = t[b * F + f]; s += v; s2 += v * v; }
  float m = s * (1.f / BB);
  float var = s2 * (1.f / BB) - m * m;
  float r = rsqrtf(var + 1e-5f);
  for (int b = 0; b < BB; ++b) {
    float v = (t[b * F + f] - m) * r;
    t[b * F + f] = v >= 0.f ? v : 0.2f * v;
  }
}

// ---------------------------------------------------------------- host side

static inline void run_conv(const float* in, int inBS, int C, int O, const float* w,
                            float* z, hipStream_t st) {
  if (O % 8 == 0)
    conv_kernel<8><<<dim3(NN / 256, O / 8, BB), 256, 0, st>>>(in, inBS, C, w, z, O);
  else  // O == 3
    conv_kernel<3><<<dim3(NN / 256, 1, BB), 256, 0, st>>>(in, inBS, C, w, z, O);
}

struct SAW { const float *wq, *wk, *wv, *wc; };

template <int C>
static inline void run_sa(const float* xin, int xbs, SAW w,
                          float* att, float* z, float* h, float* sq, int* idx,
                          float* cval, int* cidx,
                          float* mean, float* rstd, hipStream_t st) {
  sq_kernel<<<BB * NN / 256, 256, 0, st>>>(xin, xbs, C, sq);
  knn_tile_kernel<C><<<dim3(NN / 256, SPLIT, BB), 256, 0, st>>>(xin, xbs, sq, cval, cidx);
  knn_merge_kernel<<<BB * NN / 256, 256, 0, st>>>(cval, cidx, idx);
  att_kernel<<<BB * NN, 128, 0, st>>>(xin, xbs, C, idx, w.wq, w.wk, w.wv, att);
  run_conv(att, C * NN, C, C, w.wc, z, st);
  bn_stats_kernel<<<C, 256, 0, st>>>(z, C, mean, rstd);
  bn_apply_kernel<<<dim3(NN / 256, C, BB), 256, 0, st>>>(z, C, mean, rstd, h, 2 * C * NN, 0);
  copy_kernel<<<dim3(NN / 256, C, BB), 256, 0, st>>>(xin, xbs, h, 2 * C * NN, C);
}

static inline void run_conv_bn(const float* in, int inBS, int Cin, int O, const float* w,
                               float* z, float* out, int outBS, int c0,
                               float* mean, float* rstd, hipStream_t st) {
  run_conv(in, inBS, Cin, O, w, z, st);
  bn_stats_kernel<<<O, 256, 0, st>>>(z, O, mean, rstd);
  bn_apply_kernel<<<dim3(NN / 256, O, BB), 256, 0, st>>>(z, O, mean, rstd, out, outBS, c0);
}

extern "C" void kernel_launch(void* const* d_in, const int* in_sizes, int n_in,
                              void* d_out, int out_size, void* d_ws, size_t ws_size,
                              hipStream_t stream) {
  const float* x = (const float*)d_in[0];
  SAW sa1{(const float*)d_in[1], (const float*)d_in[2], (const float*)d_in[3], (const float*)d_in[4]};
  SAW sa2{(const float*)d_in[5], (const float*)d_in[6], (const float*)d_in[7], (const float*)d_in[8]};
  SAW sa3{(const float*)d_in[9], (const float*)d_in[10], (const float*)d_in[11], (const float*)d_in[12]};
  SAW sa4{(const float*)d_in[13], (const float*)d_in[14], (const float*)d_in[15], (const float*)d_in[16]};
  const float* conv1_w = (const float*)d_in[17];
  const float* conv2_w = (const float*)d_in[18];
  const float* conv3_w = (const float*)d_in[19];
  const float* conv4_w = (const float*)d_in[20];
  const float* conv5_w = (const float*)d_in[21];
  const float* lin1_w = (const float*)d_in[22];
  const float* lin1_b = (const float*)d_in[23];
  const float* lin2_w = (const float*)d_in[24];
  const float* lin2_b = (const float*)d_in[25];
  const float* lin3_w = (const float*)d_in[26];
  const float* lin3_b = (const float*)d_in[27];

  char* ws = (char*)d_ws;
  size_t off = 0;
  auto take = [&](size_t bytes) -> void* {
    void* p = ws + off;
    off += (bytes + 255) & ~(size_t)255;
    return p;
  };
  float* sq   = (float*)take((size_t)BB * NN * 4);
  int*   idx  = (int*)take((size_t)BB * NN * KNB * 4);
  float* cval = (float*)take((size_t)BB * NN * SPLIT * KNB * 4);
  int*   cidx = (int*)take((size_t)BB * NN * SPLIT * KNB * 4);
  float* att  = (float*)take((size_t)BB * 128 * NN * 4);
  float* h    = (float*)take((size_t)BB * 256 * NN * 4);
  float* z    = (float*)take((size_t)BB * 1024 * NN * 4);
  float* xc   = (float*)take((size_t)BB * 512 * NN * 4);
  float* mean = (float*)take(1024 * 4);
  float* rstd = (float*)take(1024 * 4);
  float* p    = (float*)take((size_t)BB * 2048 * 4);
  float* t1   = (float*)take((size_t)BB * 512 * 4);
  float* t2   = (float*)take((size_t)BB * 256 * 4);
  (void)ws_size; (void)n_in; (void)in_sizes; (void)out_size;

  // SA1 (C=3) -> h [B,6,N]
  run_sa<3>(x, 3 * NN, sa1, att, z, h, sq, idx, cval, cidx, mean, rstd, stream);
  // conv1: [B,6,N] -> x1 = xc[:,0:64,:]
  run_conv_bn(h, 6 * NN, 6, 64, conv1_w, z, xc, 512 * NN, 0, mean, rstd, stream);
  // SA2 (C=64) on x1 -> h [B,128,N]
  run_sa<64>(xc + 0 * NN, 512 * NN, sa2, att, z, h, sq, idx, cval, cidx, mean, rstd, stream);
  // conv2 -> x2 = xc[:,64:128,:]
  run_conv_bn(h, 128 * NN, 128, 64, conv2_w, z, xc, 512 * NN, 64, mean, rstd, stream);
  // SA3 (C=64) on x2 -> h [B,128,N]
  run_sa<64>(xc + 64 * NN, 512 * NN, sa3, att, z, h, sq, idx, cval, cidx, mean, rstd, stream);
  // conv3 -> x3 = xc[:,128:256,:]
  run_conv_bn(h, 128 * NN, 128, 128, conv3_w, z, xc, 512 * NN, 128, mean, rstd, stream);
  // SA4 (C=128) on x3 -> h [B,256,N]
  run_sa<128>(xc + 128 * NN, 512 * NN, sa4, att, z, h, sq, idx, cval, cidx, mean, rstd, stream);
  // conv4 -> x4 = xc[:,256:512,:]
  run_conv_bn(h, 256 * NN, 256, 256, conv4_w, z, xc, 512 * NN, 256, mean, rstd, stream);
  // conv5: xc [B,512,N] -> x5 (in place in z) [B,1024,N]
  run_conv_bn(xc, 512 * NN, 512, 1024, conv5_w, z, z, 1024 * NN, 0, mean, rstd, stream);
  // pool -> p [B,2048]
  pool_kernel<<<dim3(1024, BB), 256, 0, stream>>>(z, p);
  // lin1 + bn + lrelu
  linear_kernel<<<(BB * 512 + 255) / 256, 256, 0, stream>>>(p, 2048, 512, lin1_w, lin1_b, t1);
  bnf_kernel<<<2, 256, 0, stream>>>(t1, 512);
  // lin2 + bn + lrelu
  linear_kernel<<<(BB * 256 + 255) / 256, 256, 0, stream>>>(t1, 512, 256, lin2_w, lin2_b, t2);
  bnf_kernel<<<1, 256, 0, stream>>>(t2, 256);
  // lin3 -> out
  linear_kernel<<<(BB * 40 + 255) / 256, 256, 0, stream>>>(t2, 256, 40, lin3_w, lin3_b, (float*)d_out);
}

// Round 3
// 40650.656 us; speedup vs baseline: 1.6976x; 1.0660x over previous
//
#include <hip/hip_runtime.h>
#include <math.h>

#define BB 8
#define NN 2048
#define KNB 20
#define SPLIT 8

// ---------------------------------------------------------------- kernels

__global__ __launch_bounds__(256) void sq_kernel(const float* __restrict__ x, int bs, int C,
                                                 float* __restrict__ sq) {
  int t = blockIdx.x * blockDim.x + threadIdx.x;
  int b = t / NN, n = t % NN;
  const float* xp = x + b * bs + n;
  float s = 0.f;
  for (int c = 0; c < C; ++c) { float v = xp[c * NN]; s += v * v; }
  sq[t] = s;
}

// Tiled kNN: block = 256 threads, thread owns one n. m-range = NN/SPLIT per
// block, staged in LDS tiles of TM=32 (read as wave-uniform float4 broadcasts).
// Per-thread top-20 in REGISTERS with fully-unrolled branchless insert
// (no dynamic register indexing -> no scratch spill). __launch_bounds__(256,2)
// so the compiler gets 256 VGPRs (default-1024 assumption capped us at 64 and
// spilled acc[] to scratch = 52 GB of HBM traffic last round).
// Ranking value: 2*dot(xn,xm) - sq[m] (same order as reference pd; -sq[n] is
// a per-n constant).
template <int C>
__global__ __launch_bounds__(256, 2) void knn_tile_kernel(
    const float* __restrict__ x, int bs, const float* __restrict__ sq,
    float* __restrict__ cand_val, int* __restrict__ cand_idx) {
  constexpr int TM = 32;
  const int tid = threadIdx.x;                 // 0..255
  const int n = blockIdx.x * 256 + tid;        // this thread's point
  const int sp = blockIdx.y;
  const int b = blockIdx.z;
  const int MR = NN / SPLIT;                   // 256 m per block
  const int m0base = sp * MR;

  __shared__ float xm[C * TM];
  __shared__ float sqm[TM];

  float best[KNB]; int bidx[KNB];
#pragma unroll
  for (int k = 0; k < KNB; ++k) { best[k] = -INFINITY; bidx[k] = 0; }

  const float* xb = x + b * bs;

  for (int t = 0; t < MR / TM; ++t) {
    const int m0 = m0base + t * TM;
    __syncthreads();
    for (int i = tid; i < C * TM; i += 256) {
      int c = i / TM, ml = i % TM;
      xm[i] = xb[c * NN + m0 + ml];
    }
    if (tid < TM) sqm[tid] = sq[b * NN + m0 + tid];
    __syncthreads();

    float acc[TM];
#pragma unroll
    for (int ml = 0; ml < TM; ++ml) acc[ml] = 0.f;

    constexpr int CH = (C / 8) * 8;
#pragma unroll
    for (int c0 = 0; c0 < CH; c0 += 8) {
      float xnr[8];
#pragma unroll
      for (int i = 0; i < 8; ++i) xnr[i] = xb[(c0 + i) * NN + n];
#pragma unroll
      for (int i = 0; i < 8; ++i) {
        const float4* xv = (const float4*)&xm[(c0 + i) * TM];
#pragma unroll
        for (int q = 0; q < TM / 4; ++q) {
          float4 v = xv[q];
          acc[q * 4 + 0] += xnr[i] * v.x;
          acc[q * 4 + 1] += xnr[i] * v.y;
          acc[q * 4 + 2] += xnr[i] * v.z;
          acc[q * 4 + 3] += xnr[i] * v.w;
        }
      }
    }
#pragma unroll
    for (int c = CH; c < C; ++c) {
      float xn1 = xb[c * NN + n];
      const float4* xv = (const float4*)&xm[c * TM];
#pragma unroll
      for (int q = 0; q < TM / 4; ++q) {
        float4 v = xv[q];
        acc[q * 4 + 0] += xn1 * v.x;
        acc[q * 4 + 1] += xn1 * v.y;
        acc[q * 4 + 2] += xn1 * v.z;
        acc[q * 4 + 3] += xn1 * v.w;
      }
    }

    // selection: branchless unrolled insert into register-resident sorted list
#pragma unroll
    for (int ml = 0; ml < TM; ++ml) {
      float pdv = 2.f * acc[ml] - sqm[ml];
      int m = m0 + ml;
      if (pdv > best[KNB - 1] && m != n) {
#pragma unroll
        for (int j = KNB - 1; j > 0; --j) {
          bool up = pdv > best[j];
          bool fromprev = pdv > best[j - 1];
          float nv = fromprev ? best[j - 1] : pdv;
          int ni = fromprev ? bidx[j - 1] : m;
          best[j] = up ? nv : best[j];
          bidx[j] = up ? ni : bidx[j];
        }
        bool up0 = pdv > best[0];
        best[0] = up0 ? pdv : best[0];
        bidx[0] = up0 ? m : bidx[0];
      }
    }
  }

  float* cv = cand_val + ((size_t)(b * NN + n) * SPLIT + sp) * KNB;
  int* ci = cand_idx + ((size_t)(b * NN + n) * SPLIT + sp) * KNB;
#pragma unroll
  for (int k = 0; k < KNB; ++k) { cv[k] = best[k]; ci[k] = bidx[k]; }
}

// merge SPLIT sorted 20-lists per point into final top-20 indices
__global__ __launch_bounds__(256) void knn_merge_kernel(const float* __restrict__ cand_val,
                                                        const int* __restrict__ cand_idx,
                                                        int* __restrict__ idx) {
  int t = blockIdx.x * 256 + threadIdx.x;  // b*NN+n
  if (t >= BB * NN) return;
  const float* cv = cand_val + (size_t)t * SPLIT * KNB;
  const int* ci = cand_idx + (size_t)t * SPLIT * KNB;
  int pos[SPLIT];
#pragma unroll
  for (int s = 0; s < SPLIT; ++s) pos[s] = 0;
  int* op = idx + (size_t)t * KNB;
  for (int k = 0; k < KNB; ++k) {
    float best = -INFINITY;
    int bsel = 0, baddr = 0;
#pragma unroll
    for (int s = 0; s < SPLIT; ++s) {
      float v = cv[s * KNB + pos[s]];
      if (v > best) { best = v; bsel = s; baddr = s * KNB + pos[s]; }
    }
    op[k] = ci[baddr];
#pragma unroll
    for (int s = 0; s < SPLIT; ++s)
      if (s == bsel) pos[s]++;
  }
}

// one block (128 thr) per point. out = wv @ (sum_k softmax_k * nb_k - f)
__global__ __launch_bounds__(128) void att_kernel(const float* __restrict__ x, int bs, int C,
                                                  const int* __restrict__ idx,
                                                  const float* __restrict__ wq,
                                                  const float* __restrict__ wk,
                                                  const float* __restrict__ wv,
                                                  float* __restrict__ att) {
  int n = blockIdx.x % NN;
  int b = blockIdx.x / NN;
  int tid = threadIdx.x;
  __shared__ float f[128], q[128], qk[128], agg[128];
  __shared__ float s[KNB];
  __shared__ float nb[KNB][129];
  __shared__ int nidx[KNB];
  const float* xb = x + b * bs;
  for (int c = tid; c < C; c += 128) f[c] = xb[c * NN + n];
  if (tid < KNB) nidx[tid] = idx[(b * NN + n) * KNB + tid];
  __syncthreads();
  for (int kc = tid; kc < KNB * C; kc += 128) {
    int k = kc / C, c = kc - k * C;
    nb[k][c] = xb[c * NN + nidx[k]];
  }
  __syncthreads();
  if (tid < C) {
    float a = 0.f;
    for (int c = 0; c < C; ++c) a += f[c] * wq[tid * C + c];
    q[tid] = a;
  }
  __syncthreads();
  if (tid < C) {
    float a = 0.f;
    for (int e = 0; e < C; ++e) a += q[e] * wk[e * C + tid];
    qk[tid] = a;
  }
  __syncthreads();
  if (tid < KNB) {
    float a = 0.f;
    for (int c = 0; c < C; ++c) a += nb[tid][c] * qk[c];
    s[tid] = a / sqrtf((float)C);
  }
  __syncthreads();
  if (tid == 0) {
    float mx = -INFINITY;
    for (int k = 0; k < KNB; ++k) mx = fmaxf(mx, s[k]);
    float sum = 0.f;
    for (int k = 0; k < KNB; ++k) { s[k] = expf(s[k] - mx); sum += s[k]; }
    float inv = 1.f / sum;
    for (int k = 0; k < KNB; ++k) s[k] *= inv;
  }
  __syncthreads();
  if (tid < C) {
    float a = 0.f;
    for (int k = 0; k < KNB; ++k) a += s[k] * nb[k][tid];
    agg[tid] = a - f[tid];
  }
  __syncthreads();
  if (tid < C) {
    float a = 0.f;
    for (int c = 0; c < C; ++c) a += wv[tid * C + c] * agg[c];
    att[(b * C + tid) * NN + n] = a;
  }
}

// z[b,o,n] = sum_c w[o,c] * in[b,c,n]; each thread does TO consecutive o's
template <int TO>
__global__ __launch_bounds__(256) void conv_kernel(const float* __restrict__ in, int inBS, int C,
                                                   const float* __restrict__ w,
                                                   float* __restrict__ z, int O) {
  int n = blockIdx.x * blockDim.x + threadIdx.x;
  int o0 = blockIdx.y * TO;
  int b = blockIdx.z;
  const float* ip = in + b * inBS + n;
  const float* wp = w + o0 * C;
  float acc[TO];
#pragma unroll
  for (int j = 0; j < TO; ++j) acc[j] = 0.f;
  for (int c = 0; c < C; ++c) {
    float v = ip[c * NN];
#pragma unroll
    for (int j = 0; j < TO; ++j) acc[j] += v * wp[j * C + c];
  }
#pragma unroll
  for (int j = 0; j < TO; ++j) z[(b * O + o0 + j) * NN + n] = acc[j];
}

__global__ __launch_bounds__(256) void bn_stats_kernel(const float* __restrict__ z, int O,
                                                       float* __restrict__ mean,
                                                       float* __restrict__ rstd) {
  int o = blockIdx.x;
  __shared__ float s1[256], s2[256];
  float a1 = 0.f, a2 = 0.f;
  for (int i = threadIdx.x; i < BB * NN; i += 256) {
    int b = i / NN, n = i % NN;
    float v = z[(b * O + o) * NN + n];
    a1 += v; a2 += v * v;
  }
  s1[threadIdx.x] = a1; s2[threadIdx.x] = a2;
  __syncthreads();
  for (int st = 128; st > 0; st >>= 1) {
    if (threadIdx.x < st) {
      s1[threadIdx.x] += s1[threadIdx.x + st];
      s2[threadIdx.x] += s2[threadIdx.x + st];
    }
    __syncthreads();
  }
  if (threadIdx.x == 0) {
    float m = s1[0] / (BB * NN);
    float var = s2[0] / (BB * NN) - m * m;
    mean[o] = m;
    rstd[o] = rsqrtf(var + 1e-5f);
  }
}

__global__ __launch_bounds__(256) void bn_apply_kernel(const float* __restrict__ z, int O,
                                                       const float* __restrict__ mean,
                                                       const float* __restrict__ rstd,
                                                       float* __restrict__ out, int outBS, int c0) {
  int n = blockIdx.x * blockDim.x + threadIdx.x;
  int o = blockIdx.y, b = blockIdx.z;
  float v = (z[(b * O + o) * NN + n] - mean[o]) * rstd[o];
  out[b * outBS + (c0 + o) * NN + n] = v >= 0.f ? v : 0.2f * v;
}

__global__ __launch_bounds__(256) void copy_kernel(const float* __restrict__ x, int bs,
                                                   float* __restrict__ out, int outBS, int c0) {
  int n = blockIdx.x * blockDim.x + threadIdx.x;
  int c = blockIdx.y, b = blockIdx.z;
  out[b * outBS + (c0 + c) * NN + n] = x[b * bs + c * NN + n];
}

__global__ __launch_bounds__(256) void pool_kernel(const float* __restrict__ z,
                                                   float* __restrict__ p) {
  int o = blockIdx.x, b = blockIdx.y;
  const float* zp = z + (b * 1024 + o) * NN;
  __shared__ float smax[256], ssum[256];
  float mx = -INFINITY, sm = 0.f;
  for (int n = threadIdx.x; n < NN; n += 256) {
    float v = zp[n];
    mx = fmaxf(mx, v); sm += v;
  }
  smax[threadIdx.x] = mx; ssum[threadIdx.x] = sm;
  __syncthreads();
  for (int st = 128; st > 0; st >>= 1) {
    if (threadIdx.x < st) {
      smax[threadIdx.x] = fmaxf(smax[threadIdx.x], smax[threadIdx.x + st]);
      ssum[threadIdx.x] += ssum[threadIdx.x + st];
    }
    __syncthreads();
  }
  if (threadIdx.x == 0) {
    p[b * 2048 + o] = smax[0];
    p[b * 2048 + 1024 + o] = ssum[0] * (1.f / NN);
  }
}

// one wave per output element (b,f): coalesced weight reads + shuffle reduce
__global__ __launch_bounds__(64) void linear_kernel(const float* __restrict__ in, int IN, int OUT,
                                                    const float* __restrict__ w,
                                                    const float* __restrict__ bias,
                                                    float* __restrict__ out) {
  int o = blockIdx.x;          // b*OUT + f
  int b = o / OUT, f = o % OUT;
  const float* ip = in + b * IN;
  const float* wp = w + f * IN;
  float a = 0.f;
  for (int i = threadIdx.x; i < IN; i += 64) a += ip[i] * wp[i];
#pragma unroll
  for (int s = 32; s > 0; s >>= 1) a += __shfl_down(a, s);
  if (threadIdx.x == 0) out[o] = a + bias[f];
}

__global__ __launch_bounds__(256) void bnf_kernel(float* __restrict__ t, int F) {
  int f = blockIdx.x * blockDim.x + threadIdx.x;
  if (f >= F) return;
  float s = 0.f, s2 = 0.f;
  for (int b = 0; b < BB; ++b) { float v = t[b * F + f]; s += v; s2 += v * v; }
  float m = s * (1.f / BB);
  float var = s2 * (1.f / BB) - m * m;
  float r = rsqrtf(var + 1e-5f);
  for (int b = 0; b < BB; ++b) {
    float v = (t[b * F + f] - m) * r;
    t[b * F + f] = v >= 0.f ? v : 0.2f * v;
  }
}

// ---------------------------------------------------------------- host side

static inline void run_conv(const float* in, int inBS, int C, int O, const float* w,
                            float* z, hipStream_t st) {
  if (O % 8 == 0)
    conv_kernel<8><<<dim3(NN / 256, O / 8, BB), 256, 0, st>>>(in, inBS, C, w, z, O);
  else  // O == 3
    conv_kernel<3><<<dim3(NN / 256, 1, BB), 256, 0, st>>>(in, inBS, C, w, z, O);
}

struct SAW { const float *wq, *wk, *wv, *wc; };

template <int C>
static inline void run_sa(const float* xin, int xbs, SAW w,
                          float* att, float* z, float* h, float* sq, int* idx,
                          float* cval, int* cidx,
                          float* mean, float* rstd, hipStream_t st) {
  sq_kernel<<<BB * NN / 256, 256, 0, st>>>(xin, xbs, C, sq);
  knn_tile_kernel<C><<<dim3(NN / 256, SPLIT, BB), 256, 0, st>>>(xin, xbs, sq, cval, cidx);
  knn_merge_kernel<<<BB * NN / 256, 256, 0, st>>>(cval, cidx, idx);
  att_kernel<<<BB * NN, 128, 0, st>>>(xin, xbs, C, idx, w.wq, w.wk, w.wv, att);
  run_conv(att, C * NN, C, C, w.wc, z, st);
  bn_stats_kernel<<<C, 256, 0, st>>>(z, C, mean, rstd);
  bn_apply_kernel<<<dim3(NN / 256, C, BB), 256, 0, st>>>(z, C, mean, rstd, h, 2 * C * NN, 0);
  copy_kernel<<<dim3(NN / 256, C, BB), 256, 0, st>>>(xin, xbs, h, 2 * C * NN, C);
}

static inline void run_conv_bn(const float* in, int inBS, int Cin, int O, const float* w,
                               float* z, float* out, int outBS, int c0,
                               float* mean, float* rstd, hipStream_t st) {
  run_conv(in, inBS, Cin, O, w, z, st);
  bn_stats_kernel<<<O, 256, 0, st>>>(z, O, mean, rstd);
  bn_apply_kernel<<<dim3(NN / 256, O, BB), 256, 0, st>>>(z, O, mean, rstd, out, outBS, c0);
}

extern "C" void kernel_launch(void* const* d_in, const int* in_sizes, int n_in,
                              void* d_out, int out_size, void* d_ws, size_t ws_size,
                              hipStream_t stream) {
  const float* x = (const float*)d_in[0];
  SAW sa1{(const float*)d_in[1], (const float*)d_in[2], (const float*)d_in[3], (const float*)d_in[4]};
  SAW sa2{(const float*)d_in[5], (const float*)d_in[6], (const float*)d_in[7], (const float*)d_in[8]};
  SAW sa3{(const float*)d_in[9], (const float*)d_in[10], (const float*)d_in[11], (const float*)d_in[12]};
  SAW sa4{(const float*)d_in[13], (const float*)d_in[14], (const float*)d_in[15], (const float*)d_in[16]};
  const float* conv1_w = (const float*)d_in[17];
  const float* conv2_w = (const float*)d_in[18];
  const float* conv3_w = (const float*)d_in[19];
  const float* conv4_w = (const float*)d_in[20];
  const float* conv5_w = (const float*)d_in[21];
  const float* lin1_w = (const float*)d_in[22];
  const float* lin1_b = (const float*)d_in[23];
  const float* lin2_w = (const float*)d_in[24];
  const float* lin2_b = (const float*)d_in[25];
  const float* lin3_w = (const float*)d_in[26];
  const float* lin3_b = (const float*)d_in[27];

  char* ws = (char*)d_ws;
  size_t off = 0;
  auto take = [&](size_t bytes) -> void* {
    void* p = ws + off;
    off += (bytes + 255) & ~(size_t)255;
    return p;
  };
  float* sq   = (float*)take((size_t)BB * NN * 4);
  int*   idx  = (int*)take((size_t)BB * NN * KNB * 4);
  float* cval = (float*)take((size_t)BB * NN * SPLIT * KNB * 4);
  int*   cidx = (int*)take((size_t)BB * NN * SPLIT * KNB * 4);
  float* att  = (float*)take((size_t)BB * 128 * NN * 4);
  float* h    = (float*)take((size_t)BB * 256 * NN * 4);
  float* z    = (float*)take((size_t)BB * 1024 * NN * 4);
  float* xc   = (float*)take((size_t)BB * 512 * NN * 4);
  float* mean = (float*)take(1024 * 4);
  float* rstd = (float*)take(1024 * 4);
  float* p    = (float*)take((size_t)BB * 2048 * 4);
  float* t1   = (float*)take((size_t)BB * 512 * 4);
  float* t2   = (float*)take((size_t)BB * 256 * 4);
  (void)ws_size; (void)n_in; (void)in_sizes; (void)out_size;

  // SA1 (C=3) -> h [B,6,N]
  run_sa<3>(x, 3 * NN, sa1, att, z, h, sq, idx, cval, cidx, mean, rstd, stream);
  // conv1: [B,6,N] -> x1 = xc[:,0:64,:]
  run_conv_bn(h, 6 * NN, 6, 64, conv1_w, z, xc, 512 * NN, 0, mean, rstd, stream);
  // SA2 (C=64) on x1 -> h [B,128,N]
  run_sa<64>(xc + 0 * NN, 512 * NN, sa2, att, z, h, sq, idx, cval, cidx, mean, rstd, stream);
  // conv2 -> x2 = xc[:,64:128,:]
  run_conv_bn(h, 128 * NN, 128, 64, conv2_w, z, xc, 512 * NN, 64, mean, rstd, stream);
  // SA3 (C=64) on x2 -> h [B,128,N]
  run_sa<64>(xc + 64 * NN, 512 * NN, sa3, att, z, h, sq, idx, cval, cidx, mean, rstd, stream);
  // conv3 -> x3 = xc[:,128:256,:]
  run_conv_bn(h, 128 * NN, 128, 128, conv3_w, z, xc, 512 * NN, 128, mean, rstd, stream);
  // SA4 (C=128) on x3 -> h [B,256,N]
  run_sa<128>(xc + 128 * NN, 512 * NN, sa4, att, z, h, sq, idx, cval, cidx, mean, rstd, stream);
  // conv4 -> x4 = xc[:,256:512,:]
  run_conv_bn(h, 256 * NN, 256, 256, conv4_w, z, xc, 512 * NN, 256, mean, rstd, stream);
  // conv5: xc [B,512,N] -> x5 (in place in z) [B,1024,N]
  run_conv_bn(xc, 512 * NN, 512, 1024, conv5_w, z, z, 1024 * NN, 0, mean, rstd, stream);
  // pool -> p [B,2048]
  pool_kernel<<<dim3(1024, BB), 256, 0, stream>>>(z, p);
  // lin1 + bn + lrelu
  linear_kernel<<<BB * 512, 64, 0, stream>>>(p, 2048, 512, lin1_w, lin1_b, t1);
  bnf_kernel<<<2, 256, 0, stream>>>(t1, 512);
  // lin2 + bn + lrelu
  linear_kernel<<<BB * 256, 64, 0, stream>>>(t1, 512, 256, lin2_w, lin2_b, t2);
  bnf_kernel<<<1, 256, 0, stream>>>(t2, 256);
  // lin3 -> out
  linear_kernel<<<BB * 40, 64, 0, stream>>>(t2, 256, 40, lin3_w, lin3_b, (float*)d_out);
}

// Round 4
// 3009.772 us; speedup vs baseline: 22.9281x; 13.5062x over previous
//
#include <hip/hip_runtime.h>
#include <math.h>

#define BB 8
#define NN 2048
#define KNB 20

// ---------------------------------------------------------------- sq
__global__ __launch_bounds__(256) void sq_kernel(const float* __restrict__ x, int bs, int C,
                                                 float* __restrict__ sq) {
  int t = blockIdx.x * blockDim.x + threadIdx.x;
  int b = t / NN, n = t % NN;
  const float* xp = x + (size_t)b * bs + n;
  float s = 0.f;
  for (int c = 0; c < C; ++c) { float v = xp[c * NN]; s += v * v; }
  sq[t] = s;
}

// ---------------------------------------------------------------- M = wk^T wq
// M[c][c'] = sum_e wk[e*C+c] * wq[e*C+c']   (row-major [o=c][k=c'])
__global__ __launch_bounds__(256) void mprep_kernel(const float* __restrict__ wq,
                                                    const float* __restrict__ wk, int C,
                                                    float* __restrict__ M) {
  int T = blockIdx.x * 256 + threadIdx.x;
  if (T >= C * C) return;
  int c = T / C, cp = T % C;
  float a = 0.f;
  for (int e = 0; e < C; ++e) a += wk[e * C + c] * wq[e * C + cp];
  M[c * C + cp] = a;
}

// ---------------------------------------------------------------- pd GEMM
// P[bl][n][m] = 2*sum_c x[b][c][n]*x[b][c][m] - sq[b][m]; 64x64 tile, 4x4/thread.
__global__ __launch_bounds__(256, 2) void pd_gemm_kernel(
    const float* __restrict__ x, int bs, int C, const float* __restrict__ sq,
    float* __restrict__ P, int b_base) {
  const int b = b_base + blockIdx.z;
  const int n0 = blockIdx.x * 64, m0 = blockIdx.y * 64;
  const int tid = threadIdx.x;
  const int tm = tid & 15, tn = tid >> 4;  // tm -> m (coalesced stores)
  __shared__ float As[16][64], Bs[16][64];
  const float* xb = x + (size_t)b * bs;
  float acc[4][4];
#pragma unroll
  for (int i = 0; i < 4; ++i)
#pragma unroll
    for (int j = 0; j < 4; ++j) acc[i][j] = 0.f;

  for (int k0 = 0; k0 < C; k0 += 16) {
    __syncthreads();
#pragma unroll
    for (int it = 0; it < 4; ++it) {
      int i = it * 256 + tid;
      int kc = i >> 6, l = i & 63;
      bool ok = (k0 + kc) < C;
      As[kc][l] = ok ? xb[(k0 + kc) * NN + n0 + l] : 0.f;
      Bs[kc][l] = ok ? xb[(k0 + kc) * NN + m0 + l] : 0.f;
    }
    __syncthreads();
#pragma unroll
    for (int kc = 0; kc < 16; ++kc) {
      float4 a = *(const float4*)&As[kc][tn * 4];
      float4 bv = *(const float4*)&Bs[kc][tm * 4];
      acc[0][0] += a.x * bv.x; acc[0][1] += a.x * bv.y; acc[0][2] += a.x * bv.z; acc[0][3] += a.x * bv.w;
      acc[1][0] += a.y * bv.x; acc[1][1] += a.y * bv.y; acc[1][2] += a.y * bv.z; acc[1][3] += a.y * bv.w;
      acc[2][0] += a.z * bv.x; acc[2][1] += a.z * bv.y; acc[2][2] += a.z * bv.z; acc[2][3] += a.z * bv.w;
      acc[3][0] += a.w * bv.x; acc[3][1] += a.w * bv.y; acc[3][2] += a.w * bv.z; acc[3][3] += a.w * bv.w;
    }
  }
  float4 sq4 = *(const float4*)&sq[b * NN + m0 + tm * 4];
#pragma unroll
  for (int i = 0; i < 4; ++i) {
    float4 o;
    o.x = 2.f * acc[i][0] - sq4.x;
    o.y = 2.f * acc[i][1] - sq4.y;
    o.z = 2.f * acc[i][2] - sq4.z;
    o.w = 2.f * acc[i][3] - sq4.w;
    *(float4*)&P[((size_t)blockIdx.z * NN + n0 + tn * 4 + i) * NN + m0 + tm * 4] = o;
  }
}

// ---------------------------------------------------------------- top-20 per row
// block 256 per (n, bl): 8 vals/lane in regs; 20x (local argmax -> wave shuffle
// argmax -> block argmax -> owner masks slot).
__global__ __launch_bounds__(256) void topk_kernel(const float* __restrict__ P,
                                                   int* __restrict__ idx, int b_base) {
  const int n = blockIdx.x;
  const int bl = blockIdx.y;
  const int b = b_base + bl;
  const int tid = threadIdx.x;
  const float* row = P + ((size_t)bl * NN + n) * NN;
  float v[8];
#pragma unroll
  for (int j = 0; j < 8; ++j) {
    int m = j * 256 + tid;
    float val = row[m];
    v[j] = (m == n) ? -INFINITY : val;
  }
  __shared__ float wvv[4];
  __shared__ int wmm[4];
  __shared__ int swin;
  int* op = idx + (size_t)(b * NN + n) * KNB;
  for (int k = 0; k < KNB; ++k) {
    float bv = v[0]; int bj = 0;
#pragma unroll
    for (int j = 1; j < 8; ++j)
      if (v[j] > bv) { bv = v[j]; bj = j; }
    int bm = bj * 256 + tid;
#pragma unroll
    for (int s = 32; s > 0; s >>= 1) {
      float ov = __shfl_down(bv, s);
      int om = __shfl_down(bm, s);
      if (ov > bv) { bv = ov; bm = om; }
    }
    if ((tid & 63) == 0) { wvv[tid >> 6] = bv; wmm[tid >> 6] = bm; }
    __syncthreads();
    if (tid == 0) {
      float best = wvv[0]; int bsel = wmm[0];
#pragma unroll
      for (int w = 1; w < 4; ++w)
        if (wvv[w] > best) { best = wvv[w]; bsel = wmm[w]; }
      swin = bsel;
      op[k] = bsel;
    }
    __syncthreads();
    int wm = swin;
    if ((wm & 255) == tid) {
      int jj = wm >> 8;
#pragma unroll
      for (int j = 0; j < 8; ++j)
        if (j == jj) v[j] = -INFINITY;
    }
  }
}

// ---------------------------------------------------------------- conv GEMM
// z[b][o][n] = sum_c w[o*C+c] * in[b][c][n]; 64(o)x64(n) tile, 4x4/thread.
__global__ __launch_bounds__(256, 2) void conv_gemm_kernel(
    const float* __restrict__ in, int inBS, int C, int O,
    const float* __restrict__ w, float* __restrict__ z) {
  const int b = blockIdx.z;
  const int n0 = blockIdx.x * 64, o0 = blockIdx.y * 64;
  const int tid = threadIdx.x;
  const int tm = tid & 15, tn = tid >> 4;  // tm -> n (coalesced), tn -> o
  __shared__ float Ws[16][68];  // [kc][ol], padded (272B rows, 16B-aligned)
  __shared__ float Xs[16][64];  // [kc][nl]
  const float* ib = in + (size_t)b * inBS;
  float acc[4][4];
#pragma unroll
  for (int i = 0; i < 4; ++i)
#pragma unroll
    for (int j = 0; j < 4; ++j) acc[i][j] = 0.f;

  for (int k0 = 0; k0 < C; k0 += 16) {
    __syncthreads();
#pragma unroll
    for (int it = 0; it < 4; ++it) {
      int i = it * 256 + tid;
      int kc = i >> 6, nl = i & 63;
      Xs[kc][nl] = ((k0 + kc) < C) ? ib[(k0 + kc) * NN + n0 + nl] : 0.f;
      int ol = i >> 4, kc2 = i & 15;
      Ws[kc2][ol] = ((o0 + ol) < O && (k0 + kc2) < C) ? w[(o0 + ol) * C + k0 + kc2] : 0.f;
    }
    __syncthreads();
#pragma unroll
    for (int kc = 0; kc < 16; ++kc) {
      float4 a = *(const float4*)&Ws[kc][tn * 4];
      float4 bv = *(const float4*)&Xs[kc][tm * 4];
      acc[0][0] += a.x * bv.x; acc[0][1] += a.x * bv.y; acc[0][2] += a.x * bv.z; acc[0][3] += a.x * bv.w;
      acc[1][0] += a.y * bv.x; acc[1][1] += a.y * bv.y; acc[1][2] += a.y * bv.z; acc[1][3] += a.y * bv.w;
      acc[2][0] += a.z * bv.x; acc[2][1] += a.z * bv.y; acc[2][2] += a.z * bv.z; acc[2][3] += a.z * bv.w;
      acc[3][0] += a.w * bv.x; acc[3][1] += a.w * bv.y; acc[3][2] += a.w * bv.z; acc[3][3] += a.w * bv.w;
    }
  }
#pragma unroll
  for (int i = 0; i < 4; ++i) {
    int o = o0 + tn * 4 + i;
    if (o < O) {
      float4 ov;
      ov.x = acc[i][0]; ov.y = acc[i][1]; ov.z = acc[i][2]; ov.w = acc[i][3];
      *(float4*)&z[((size_t)b * O + o) * NN + n0 + tm * 4] = ov;
    }
  }
}

// ---------------------------------------------------------------- light attention
// per point: scores_k = nb_k . u_n (u = M f precomputed), softmax, AGG = sum - f.
__global__ __launch_bounds__(128) void att_light_kernel(
    const float* __restrict__ x, int bs, int C, const float* __restrict__ U,
    const int* __restrict__ idx, float* __restrict__ AGG) {
  int n = blockIdx.x % NN;
  int b = blockIdx.x / NN;
  int tid = threadIdx.x;
  __shared__ float u[128], s[KNB];
  __shared__ float nb[KNB][129];
  __shared__ int nidx[KNB];
  const float* xb = x + (size_t)b * bs;
  if (tid < KNB) nidx[tid] = idx[(size_t)(b * NN + n) * KNB + tid];
  for (int c = tid; c < C; c += 128) u[c] = U[((size_t)b * C + c) * NN + n];
  __syncthreads();
  for (int kc = tid; kc < KNB * C; kc += 128) {
    int k = kc / C, c = kc - k * C;
    nb[k][c] = xb[c * NN + nidx[k]];
  }
  __syncthreads();
  if (tid < KNB) {
    float a = 0.f;
    for (int c = 0; c < C; ++c) a += nb[tid][c] * u[c];
    s[tid] = a / sqrtf((float)C);
  }
  __syncthreads();
  if (tid == 0) {
    float mx = -INFINITY;
    for (int k = 0; k < KNB; ++k) mx = fmaxf(mx, s[k]);
    float sum = 0.f;
    for (int k = 0; k < KNB; ++k) { s[k] = expf(s[k] - mx); sum += s[k]; }
    float inv = 1.f / sum;
    for (int k = 0; k < KNB; ++k) s[k] *= inv;
  }
  __syncthreads();
  for (int c = tid; c < C; c += 128) {
    float a = 0.f;
    for (int k = 0; k < KNB; ++k) a += s[k] * nb[k][c];
    AGG[((size_t)b * C + c) * NN + n] = a - xb[c * NN + n];
  }
}

// ---------------------------------------------------------------- BN / misc
__global__ __launch_bounds__(256) void bn_stats_kernel(const float* __restrict__ z, int O,
                                                       float* __restrict__ mean,
                                                       float* __restrict__ rstd) {
  int o = blockIdx.x;
  __shared__ float s1[256], s2[256];
  float a1 = 0.f, a2 = 0.f;
  for (int i = threadIdx.x; i < BB * NN; i += 256) {
    int b = i / NN, n = i % NN;
    float v = z[((size_t)b * O + o) * NN + n];
    a1 += v; a2 += v * v;
  }
  s1[threadIdx.x] = a1; s2[threadIdx.x] = a2;
  __syncthreads();
  for (int st = 128; st > 0; st >>= 1) {
    if (threadIdx.x < st) {
      s1[threadIdx.x] += s1[threadIdx.x + st];
      s2[threadIdx.x] += s2[threadIdx.x + st];
    }
    __syncthreads();
  }
  if (threadIdx.x == 0) {
    float m = s1[0] / (BB * NN);
    float var = s2[0] / (BB * NN) - m * m;
    mean[o] = m;
    rstd[o] = rsqrtf(var + 1e-5f);
  }
}

__global__ __launch_bounds__(256) void bn_apply_kernel(const float* __restrict__ z, int O,
                                                       const float* __restrict__ mean,
                                                       const float* __restrict__ rstd,
                                                       float* __restrict__ out, int outBS, int c0) {
  int n = blockIdx.x * blockDim.x + threadIdx.x;
  int o = blockIdx.y, b = blockIdx.z;
  float v = (z[((size_t)b * O + o) * NN + n] - mean[o]) * rstd[o];
  out[(size_t)b * outBS + (c0 + o) * NN + n] = v >= 0.f ? v : 0.2f * v;
}

__global__ __launch_bounds__(256) void copy_kernel(const float* __restrict__ x, int bs,
                                                   float* __restrict__ out, int outBS, int c0) {
  int n = blockIdx.x * blockDim.x + threadIdx.x;
  int c = blockIdx.y, b = blockIdx.z;
  out[(size_t)b * outBS + (c0 + c) * NN + n] = x[(size_t)b * bs + c * NN + n];
}

__global__ __launch_bounds__(256) void pool_kernel(const float* __restrict__ z,
                                                   float* __restrict__ p) {
  int o = blockIdx.x, b = blockIdx.y;
  const float* zp = z + ((size_t)b * 1024 + o) * NN;
  __shared__ float smax[256], ssum[256];
  float mx = -INFINITY, sm = 0.f;
  for (int n = threadIdx.x; n < NN; n += 256) {
    float v = zp[n];
    mx = fmaxf(mx, v); sm += v;
  }
  smax[threadIdx.x] = mx; ssum[threadIdx.x] = sm;
  __syncthreads();
  for (int st = 128; st > 0; st >>= 1) {
    if (threadIdx.x < st) {
      smax[threadIdx.x] = fmaxf(smax[threadIdx.x], smax[threadIdx.x + st]);
      ssum[threadIdx.x] += ssum[threadIdx.x + st];
    }
    __syncthreads();
  }
  if (threadIdx.x == 0) {
    p[b * 2048 + o] = smax[0];
    p[b * 2048 + 1024 + o] = ssum[0] * (1.f / NN);
  }
}

__global__ __launch_bounds__(64) void linear_kernel(const float* __restrict__ in, int IN, int OUT,
                                                    const float* __restrict__ w,
                                                    const float* __restrict__ bias,
                                                    float* __restrict__ out) {
  int o = blockIdx.x;
  int b = o / OUT, f = o % OUT;
  const float* ip = in + (size_t)b * IN;
  const float* wp = w + (size_t)f * IN;
  float a = 0.f;
  for (int i = threadIdx.x; i < IN; i += 64) a += ip[i] * wp[i];
#pragma unroll
  for (int s = 32; s > 0; s >>= 1) a += __shfl_down(a, s);
  if (threadIdx.x == 0) out[o] = a + bias[f];
}

__global__ __launch_bounds__(256) void bnf_kernel(float* __restrict__ t, int F) {
  int f = blockIdx.x * blockDim.x + threadIdx.x;
  if (f >= F) return;
  float s = 0.f, s2 = 0.f;
  for (int b = 0; b < BB; ++b) { float v = t[b * F + f]; s += v; s2 += v * v; }
  float m = s * (1.f / BB);
  float var = s2 * (1.f / BB) - m * m;
  float r = rsqrtf(var + 1e-5f);
  for (int b = 0; b < BB; ++b) {
    float v = (t[b * F + f] - m) * r;
    t[b * F + f] = v >= 0.f ? v : 0.2f * v;
  }
}

// ---------------------------------------------------------------- host side

struct SAW { const float *wq, *wk, *wv, *wc; };

static inline void run_conv(const float* in, int inBS, int C, int O, const float* w,
                            float* z, hipStream_t st) {
  conv_gemm_kernel<<<dim3(NN / 64, (O + 63) / 64, BB), 256, 0, st>>>(in, inBS, C, O, w, z);
}

static inline void run_sa(int C, const float* xin, int xbs, SAW w,
                          float* U, float* AGG, float* z, float* h, float* sq, int* idx,
                          float* M, float* D, int nb,
                          float* mean, float* rstd, hipStream_t st) {
  sq_kernel<<<BB * NN / 256, 256, 0, st>>>(xin, xbs, C, sq);
  mprep_kernel<<<(C * C + 255) / 256, 256, 0, st>>>(w.wq, w.wk, C, M);
  for (int bb = 0; bb < BB; bb += nb) {
    pd_gemm_kernel<<<dim3(NN / 64, NN / 64, nb), 256, 0, st>>>(xin, xbs, C, sq, D, bb);
    topk_kernel<<<dim3(NN, nb), 256, 0, st>>>(D, idx, bb);
  }
  run_conv(xin, xbs, C, C, M, U, st);                       // U = M . x
  att_light_kernel<<<BB * NN, 128, 0, st>>>(xin, xbs, C, U, idx, AGG);
  run_conv(AGG, C * NN, C, C, w.wv, U, st);                 // V = wv . AGG (reuse U)
  run_conv(U, C * NN, C, C, w.wc, z, st);                   // Z = wc . V
  bn_stats_kernel<<<C, 256, 0, st>>>(z, C, mean, rstd);
  bn_apply_kernel<<<dim3(NN / 256, C, BB), 256, 0, st>>>(z, C, mean, rstd, h, 2 * C * NN, 0);
  copy_kernel<<<dim3(NN / 256, C, BB), 256, 0, st>>>(xin, xbs, h, 2 * C * NN, C);
}

static inline void run_conv_bn(const float* in, int inBS, int Cin, int O, const float* w,
                               float* z, float* out, int outBS, int c0,
                               float* mean, float* rstd, hipStream_t st) {
  run_conv(in, inBS, Cin, O, w, z, st);
  bn_stats_kernel<<<O, 256, 0, st>>>(z, O, mean, rstd);
  bn_apply_kernel<<<dim3(NN / 256, O, BB), 256, 0, st>>>(z, O, mean, rstd, out, outBS, c0);
}

extern "C" void kernel_launch(void* const* d_in, const int* in_sizes, int n_in,
                              void* d_out, int out_size, void* d_ws, size_t ws_size,
                              hipStream_t stream) {
  const float* x = (const float*)d_in[0];
  SAW sa1{(const float*)d_in[1], (const float*)d_in[2], (const float*)d_in[3], (const float*)d_in[4]};
  SAW sa2{(const float*)d_in[5], (const float*)d_in[6], (const float*)d_in[7], (const float*)d_in[8]};
  SAW sa3{(const float*)d_in[9], (const float*)d_in[10], (const float*)d_in[11], (const float*)d_in[12]};
  SAW sa4{(const float*)d_in[13], (const float*)d_in[14], (const float*)d_in[15], (const float*)d_in[16]};
  const float* conv1_w = (const float*)d_in[17];
  const float* conv2_w = (const float*)d_in[18];
  const float* conv3_w = (const float*)d_in[19];
  const float* conv4_w = (const float*)d_in[20];
  const float* conv5_w = (const float*)d_in[21];
  const float* lin1_w = (const float*)d_in[22];
  const float* lin1_b = (const float*)d_in[23];
  const float* lin2_w = (const float*)d_in[24];
  const float* lin2_b = (const float*)d_in[25];
  const float* lin3_w = (const float*)d_in[26];
  const float* lin3_b = (const float*)d_in[27];

  char* ws = (char*)d_ws;
  size_t off = 0;
  auto take = [&](size_t bytes) -> void* {
    void* p = ws + off;
    off += (bytes + 255) & ~(size_t)255;
    return p;
  };
  float* sq   = (float*)take((size_t)BB * NN * 4);
  int*   idx  = (int*)take((size_t)BB * NN * KNB * 4);
  float* M    = (float*)take((size_t)128 * 128 * 4);
  float* U    = (float*)take((size_t)BB * 128 * NN * 4);
  float* AGG  = (float*)take((size_t)BB * 128 * NN * 4);
  float* h    = (float*)take((size_t)BB * 256 * NN * 4);
  float* z    = (float*)take((size_t)BB * 1024 * NN * 4);
  float* xc   = (float*)take((size_t)BB * 512 * NN * 4);
  float* mean = (float*)take(1024 * 4);
  float* rstd = (float*)take(1024 * 4);
  float* p    = (float*)take((size_t)BB * 2048 * 4);
  float* t1   = (float*)take((size_t)BB * 512 * 4);
  float* t2   = (float*)take((size_t)BB * 256 * 4);
  (void)n_in; (void)in_sizes; (void)out_size;

  // D (distance matrix): full [B,N,N] = 134 MB if workspace allows, else
  // per-batch [1,N,N] overlaid on z (z is dead during the kNN phase).
  size_t dfull = (size_t)BB * NN * NN * 4;
  bool fullD = (ws_size > off + dfull + 4096);
  float* D = fullD ? (float*)take(dfull) : z;
  int nb = fullD ? BB : 1;

  // SA1 (C=3) -> h [B,6,N]
  run_sa(3, x, 3 * NN, sa1, U, AGG, z, h, sq, idx, M, D, nb, mean, rstd, stream);
  run_conv_bn(h, 6 * NN, 6, 64, conv1_w, z, xc, 512 * NN, 0, mean, rstd, stream);
  // SA2 (C=64) on x1 -> h [B,128,N]
  run_sa(64, xc + 0 * NN, 512 * NN, sa2, U, AGG, z, h, sq, idx, M, D, nb, mean, rstd, stream);
  run_conv_bn(h, 128 * NN, 128, 64, conv2_w, z, xc, 512 * NN, 64, mean, rstd, stream);
  // SA3 (C=64) on x2 -> h [B,128,N]
  run_sa(64, xc + 64 * NN, 512 * NN, sa3, U, AGG, z, h, sq, idx, M, D, nb, mean, rstd, stream);
  run_conv_bn(h, 128 * NN, 128, 128, conv3_w, z, xc, 512 * NN, 128, mean, rstd, stream);
  // SA4 (C=128) on x3 -> h [B,256,N]
  run_sa(128, xc + 128 * NN, 512 * NN, sa4, U, AGG, z, h, sq, idx, M, D, nb, mean, rstd, stream);
  run_conv_bn(h, 256 * NN, 256, 256, conv4_w, z, xc, 512 * NN, 256, mean, rstd, stream);
  // conv5: xc [B,512,N] -> x5 (in z) [B,1024,N]
  run_conv_bn(xc, 512 * NN, 512, 1024, conv5_w, z, z, 1024 * NN, 0, mean, rstd, stream);
  // pool -> p [B,2048]
  pool_kernel<<<dim3(1024, BB), 256, 0, stream>>>(z, p);
  // FC head
  linear_kernel<<<BB * 512, 64, 0, stream>>>(p, 2048, 512, lin1_w, lin1_b, t1);
  bnf_kernel<<<2, 256, 0, stream>>>(t1, 512);
  linear_kernel<<<BB * 256, 64, 0, stream>>>(t1, 512, 256, lin2_w, lin2_b, t2);
  bnf_kernel<<<1, 256, 0, stream>>>(t2, 256);
  linear_kernel<<<BB * 40, 64, 0, stream>>>(t2, 256, 40, lin3_w, lin3_b, (float*)d_out);
}

// Round 5
// 2989.903 us; speedup vs baseline: 23.0804x; 1.0066x over previous
//
#include <hip/hip_runtime.h>
#include <math.h>

#define BB 8
#define NN 2048
#define KNB 20

// ---------------------------------------------------------------- sq
__global__ __launch_bounds__(256) void sq_kernel(const float* __restrict__ x, int bs, int C,
                                                 float* __restrict__ sq) {
  int t = blockIdx.x * blockDim.x + threadIdx.x;
  int b = t / NN, n = t % NN;
  const float* xp = x + (size_t)b * bs + n;
  float s = 0.f;
  for (int c = 0; c < C; ++c) { float v = xp[c * NN]; s += v * v; }
  sq[t] = s;
}

// ---------------------------------------------------------------- M = wk^T wq
__global__ __launch_bounds__(256) void mprep_kernel(const float* __restrict__ wq,
                                                    const float* __restrict__ wk, int C,
                                                    float* __restrict__ M) {
  int T = blockIdx.x * 256 + threadIdx.x;
  if (T >= C * C) return;
  int c = T / C, cp = T % C;
  float a = 0.f;
  for (int e = 0; e < C; ++e) a += wk[e * C + c] * wq[e * C + cp];
  M[c * C + cp] = a;
}

// ---------------------------------------------------------------- transpose
// out[c * R + r] = in[r * Cl + c]; in batch-stride inBS, out compact R*Cl.
__global__ __launch_bounds__(256) void transpose_kernel(const float* __restrict__ in, int inBS,
                                                        int R, int Cl, float* __restrict__ out) {
  __shared__ float tile[32][33];
  int b = blockIdx.z;
  const float* ip = in + (size_t)b * inBS;
  float* op = out + (size_t)b * R * Cl;
  int c0 = blockIdx.x * 32, r0 = blockIdx.y * 32;
  int tx = threadIdx.x & 31, ty = threadIdx.x >> 5;
  for (int yy = ty; yy < 32; yy += 8) {
    int r = r0 + yy, c = c0 + tx;
    tile[yy][tx] = (r < R && c < Cl) ? ip[(size_t)r * Cl + c] : 0.f;
  }
  __syncthreads();
  for (int yy = ty; yy < 32; yy += 8) {
    int c = c0 + yy, r = r0 + tx;
    if (c < Cl && r < R) op[(size_t)c * R + r] = tile[tx][yy];
  }
}

// ---------------------------------------------------------------- pd GEMM 128-tile
// P[bl][n][m] = 2*sum_c x[c][n]*x[c][m] - sq[m]; 128x128 tile, 8x8/thread.
__global__ __launch_bounds__(256, 2) void pd_gemm128_kernel(
    const float* __restrict__ x, int bs, int C, const float* __restrict__ sq,
    float* __restrict__ P, int b_base) {
  const int b = b_base + blockIdx.z;
  const int n0 = blockIdx.x * 128, m0 = blockIdx.y * 128;
  const int tid = threadIdx.x;
  const int tm = tid & 15, tn = tid >> 4;
  __shared__ float As[16][128], Bs[16][128];
  const float* xb = x + (size_t)b * bs;
  float acc[8][8];
#pragma unroll
  for (int i = 0; i < 8; ++i)
#pragma unroll
    for (int j = 0; j < 8; ++j) acc[i][j] = 0.f;

  for (int k0 = 0; k0 < C; k0 += 16) {
    __syncthreads();
#pragma unroll
    for (int it = 0; it < 8; ++it) {
      int i = it * 256 + tid;
      int kc = i >> 7, l = i & 127;
      bool ok = (k0 + kc) < C;
      As[kc][l] = ok ? xb[(k0 + kc) * NN + n0 + l] : 0.f;
      Bs[kc][l] = ok ? xb[(k0 + kc) * NN + m0 + l] : 0.f;
    }
    __syncthreads();
#pragma unroll
    for (int kc = 0; kc < 16; ++kc) {
      float4 a0 = *(const float4*)&As[kc][tn * 4];
      float4 a1 = *(const float4*)&As[kc][64 + tn * 4];
      float4 b0 = *(const float4*)&Bs[kc][tm * 4];
      float4 b1 = *(const float4*)&Bs[kc][64 + tm * 4];
      float ar[8] = {a0.x, a0.y, a0.z, a0.w, a1.x, a1.y, a1.z, a1.w};
      float br[8] = {b0.x, b0.y, b0.z, b0.w, b1.x, b1.y, b1.z, b1.w};
#pragma unroll
      for (int i = 0; i < 8; ++i)
#pragma unroll
        for (int j = 0; j < 8; ++j) acc[i][j] += ar[i] * br[j];
    }
  }
  float4 sqa = *(const float4*)&sq[b * NN + m0 + tm * 4];
  float4 sqb = *(const float4*)&sq[b * NN + m0 + 64 + tm * 4];
#pragma unroll
  for (int h = 0; h < 2; ++h)
#pragma unroll
    for (int i = 0; i < 4; ++i) {
      int r = h * 4 + i;
      int nn = n0 + h * 64 + tn * 4 + i;
      float* prow = &P[((size_t)blockIdx.z * NN + nn) * NN + m0];
      float4 o0, o1;
      o0.x = 2.f * acc[r][0] - sqa.x; o0.y = 2.f * acc[r][1] - sqa.y;
      o0.z = 2.f * acc[r][2] - sqa.z; o0.w = 2.f * acc[r][3] - sqa.w;
      o1.x = 2.f * acc[r][4] - sqb.x; o1.y = 2.f * acc[r][5] - sqb.y;
      o1.z = 2.f * acc[r][6] - sqb.z; o1.w = 2.f * acc[r][7] - sqb.w;
      *(float4*)&prow[tm * 4] = o0;
      *(float4*)&prow[64 + tm * 4] = o1;
    }
}

// ---------------------------------------------------------------- one-wave top-20
// 64 lanes x 32 reg values; 20x (unrolled local argmax -> shuffle argmax ->
// broadcast -> compare-indexed invalidate). No LDS, no barriers, no spill.
__global__ __launch_bounds__(64) void topk_kernel(const float* __restrict__ P,
                                                  int* __restrict__ idx, int b_base) {
  const int n = blockIdx.x;
  const int bl = blockIdx.y;
  const int b = b_base + bl;
  const int lane = threadIdx.x;
  const float* row = P + ((size_t)bl * NN + n) * NN;
  const float4* rp = (const float4*)row;
  float v[32];
#pragma unroll
  for (int q = 0; q < 8; ++q) {
    float4 vv = rp[q * 64 + lane];
    int mb = q * 256 + lane * 4;
    v[q * 4 + 0] = (mb + 0 == n) ? -INFINITY : vv.x;
    v[q * 4 + 1] = (mb + 1 == n) ? -INFINITY : vv.y;
    v[q * 4 + 2] = (mb + 2 == n) ? -INFINITY : vv.z;
    v[q * 4 + 3] = (mb + 3 == n) ? -INFINITY : vv.w;
  }
  int* op = idx + (size_t)(b * NN + n) * KNB;
  for (int k = 0; k < KNB; ++k) {
    float bv = v[0]; int bj = 0;
#pragma unroll
    for (int j = 1; j < 32; ++j)
      if (v[j] > bv) { bv = v[j]; bj = j; }
    int bm = (bj >> 2) * 256 + lane * 4 + (bj & 3);
#pragma unroll
    for (int s = 32; s > 0; s >>= 1) {
      float ov = __shfl_down(bv, s);
      int om = __shfl_down(bm, s);
      if (ov > bv) { bv = ov; bm = om; }
    }
    bm = __shfl(bm, 0);
    if (lane == 0) op[k] = bm;
    if (((bm >> 2) & 63) == lane) {
      int jj = ((bm >> 8) << 2) | (bm & 3);
#pragma unroll
      for (int j = 0; j < 32; ++j)
        if (j == jj) v[j] = -INFINITY;
    }
  }
}

// ---------------------------------------------------------------- conv GEMM 64-tile
__global__ __launch_bounds__(256, 2) void conv_gemm_kernel(
    const float* __restrict__ in, int inBS, int C, int O,
    const float* __restrict__ w, float* __restrict__ z) {
  const int b = blockIdx.z;
  const int n0 = blockIdx.x * 64, o0 = blockIdx.y * 64;
  const int tid = threadIdx.x;
  const int tm = tid & 15, tn = tid >> 4;
  __shared__ float Ws[16][68];
  __shared__ float Xs[16][64];
  const float* ib = in + (size_t)b * inBS;
  float acc[4][4];
#pragma unroll
  for (int i = 0; i < 4; ++i)
#pragma unroll
    for (int j = 0; j < 4; ++j) acc[i][j] = 0.f;

  for (int k0 = 0; k0 < C; k0 += 16) {
    __syncthreads();
#pragma unroll
    for (int it = 0; it < 4; ++it) {
      int i = it * 256 + tid;
      int kc = i >> 6, nl = i & 63;
      Xs[kc][nl] = ((k0 + kc) < C) ? ib[(k0 + kc) * NN + n0 + nl] : 0.f;
      int ol = i >> 4, kc2 = i & 15;
      Ws[kc2][ol] = ((o0 + ol) < O && (k0 + kc2) < C) ? w[(o0 + ol) * C + k0 + kc2] : 0.f;
    }
    __syncthreads();
#pragma unroll
    for (int kc = 0; kc < 16; ++kc) {
      float4 a = *(const float4*)&Ws[kc][tn * 4];
      float4 bv = *(const float4*)&Xs[kc][tm * 4];
      acc[0][0] += a.x * bv.x; acc[0][1] += a.x * bv.y; acc[0][2] += a.x * bv.z; acc[0][3] += a.x * bv.w;
      acc[1][0] += a.y * bv.x; acc[1][1] += a.y * bv.y; acc[1][2] += a.y * bv.z; acc[1][3] += a.y * bv.w;
      acc[2][0] += a.z * bv.x; acc[2][1] += a.z * bv.y; acc[2][2] += a.z * bv.z; acc[2][3] += a.z * bv.w;
      acc[3][0] += a.w * bv.x; acc[3][1] += a.w * bv.y; acc[3][2] += a.w * bv.z; acc[3][3] += a.w * bv.w;
    }
  }
#pragma unroll
  for (int i = 0; i < 4; ++i) {
    int o = o0 + tn * 4 + i;
    if (o < O) {
      float4 ov;
      ov.x = acc[i][0]; ov.y = acc[i][1]; ov.z = acc[i][2]; ov.w = acc[i][3];
      *(float4*)&z[((size_t)b * O + o) * NN + n0 + tm * 4] = ov;
    }
  }
}

// ---------------------------------------------------------------- conv GEMM 128-tile
__global__ __launch_bounds__(256, 2) void conv_gemm128_kernel(
    const float* __restrict__ in, int inBS, int C, int O,
    const float* __restrict__ w, float* __restrict__ z) {
  const int b = blockIdx.z;
  const int n0 = blockIdx.x * 128, o0 = blockIdx.y * 128;
  const int tid = threadIdx.x;
  const int tm = tid & 15, tn = tid >> 4;
  __shared__ float Ws[16][132];
  __shared__ float Xs[16][128];
  const float* ib = in + (size_t)b * inBS;
  float acc[8][8];
#pragma unroll
  for (int i = 0; i < 8; ++i)
#pragma unroll
    for (int j = 0; j < 8; ++j) acc[i][j] = 0.f;

  for (int k0 = 0; k0 < C; k0 += 16) {
    __syncthreads();
#pragma unroll
    for (int it = 0; it < 8; ++it) {
      int i = it * 256 + tid;
      int kc = i >> 7, nl = i & 127;
      Xs[kc][nl] = ((k0 + kc) < C) ? ib[(k0 + kc) * NN + n0 + nl] : 0.f;
      int kc2 = i & 15, ol = i >> 4;
      Ws[kc2][ol] = ((k0 + kc2) < C) ? w[(o0 + ol) * C + k0 + kc2] : 0.f;
    }
    __syncthreads();
#pragma unroll
    for (int kc = 0; kc < 16; ++kc) {
      float4 a0 = *(const float4*)&Ws[kc][tn * 4];
      float4 a1 = *(const float4*)&Ws[kc][64 + tn * 4];
      float4 b0 = *(const float4*)&Xs[kc][tm * 4];
      float4 b1 = *(const float4*)&Xs[kc][64 + tm * 4];
      float ar[8] = {a0.x, a0.y, a0.z, a0.w, a1.x, a1.y, a1.z, a1.w};
      float br[8] = {b0.x, b0.y, b0.z, b0.w, b1.x, b1.y, b1.z, b1.w};
#pragma unroll
      for (int i = 0; i < 8; ++i)
#pragma unroll
        for (int j = 0; j < 8; ++j) acc[i][j] += ar[i] * br[j];
    }
  }
#pragma unroll
  for (int h = 0; h < 2; ++h)
#pragma unroll
    for (int i = 0; i < 4; ++i) {
      int r = h * 4 + i;
      int o = o0 + h * 64 + tn * 4 + i;
      float* zrow = &z[((size_t)b * O + o) * NN + n0];
      float4 o0v, o1v;
      o0v.x = acc[r][0]; o0v.y = acc[r][1]; o0v.z = acc[r][2]; o0v.w = acc[r][3];
      o1v.x = acc[r][4]; o1v.y = acc[r][5]; o1v.z = acc[r][6]; o1v.w = acc[r][7];
      *(float4*)&zrow[tm * 4] = o0v;
      *(float4*)&zrow[64 + tm * 4] = o1v;
    }
}

// ---------------------------------------------------------------- attention (wave/point)
// reads xT [B][N][C] (contiguous neighbor rows) and UT [B][N][C];
// writes AGGt [B][N][C] (contiguous).
template <int C>
__global__ __launch_bounds__(64) void att_wave_kernel(
    const float* __restrict__ xT, const float* __restrict__ UT,
    const int* __restrict__ idx, float* __restrict__ AGGt) {
  const int n = blockIdx.x & (NN - 1);
  const int b = blockIdx.x >> 11;
  const int lane = threadIdx.x;
  constexpr int CP = C + 1;
  __shared__ float nb[KNB][CP];
  __shared__ float sl[KNB];
  __shared__ int nidx[KNB];
  __shared__ float ul[C];
  const float* xTb = xT + (size_t)b * NN * C;
  if (lane < KNB) nidx[lane] = idx[(size_t)(b * NN + n) * KNB + lane];
  for (int c = lane; c < C; c += 64) ul[c] = UT[((size_t)b * NN + n) * C + c];
  __syncthreads();
  for (int i = lane; i < KNB * C; i += 64) {
    int k = i / C, c = i - k * C;
    nb[k][c] = xTb[(size_t)nidx[k] * C + c];
  }
  __syncthreads();
  float sv = -INFINITY;
  if (lane < KNB) {
    float a = 0.f;
#pragma unroll
    for (int c = 0; c < C; ++c) a += nb[lane][c] * ul[c];
    sv = a / sqrtf((float)C);
  }
  float mx = sv;
#pragma unroll
  for (int s = 32; s > 0; s >>= 1) mx = fmaxf(mx, __shfl_xor(mx, s));
  float e = (lane < KNB) ? expf(sv - mx) : 0.f;
  float sum = e;
#pragma unroll
  for (int s = 32; s > 0; s >>= 1) sum += __shfl_xor(sum, s);
  if (lane < KNB) sl[lane] = e / sum;
  __syncthreads();
  const float* xTn = xTb + (size_t)n * C;
  float* op = AGGt + ((size_t)b * NN + n) * C;
  for (int c = lane; c < C; c += 64) {
    float a = 0.f;
#pragma unroll
    for (int k = 0; k < KNB; ++k) a += sl[k] * nb[k][c];
    op[c] = a - xTn[c];
  }
}

// ---------------------------------------------------------------- fused BN (+LReLU)
__global__ __launch_bounds__(256) void bn_fused_kernel(const float* __restrict__ z, int O,
                                                       float* __restrict__ out, int outBS, int c0) {
  int o = blockIdx.x;
  int tid = threadIdx.x;
  __shared__ float s1[256], s2[256];
  __shared__ float smv, srv;
  float a1 = 0.f, a2 = 0.f;
  for (int i = tid; i < BB * NN; i += 256) {
    int b = i >> 11, n = i & (NN - 1);
    float v = z[((size_t)b * O + o) * NN + n];
    a1 += v; a2 += v * v;
  }
  s1[tid] = a1; s2[tid] = a2;
  __syncthreads();
  for (int st = 128; st > 0; st >>= 1) {
    if (tid < st) { s1[tid] += s1[tid + st]; s2[tid] += s2[tid + st]; }
    __syncthreads();
  }
  if (tid == 0) {
    float m = s1[0] / (BB * NN);
    float var = s2[0] / (BB * NN) - m * m;
    smv = m; srv = rsqrtf(var + 1e-5f);
  }
  __syncthreads();
  float m = smv, r = srv;
  for (int i = tid; i < BB * NN; i += 256) {
    int b = i >> 11, n = i & (NN - 1);
    float v = (z[((size_t)b * O + o) * NN + n] - m) * r;
    out[(size_t)b * outBS + (c0 + o) * NN + n] = v >= 0.f ? v : 0.2f * v;
  }
}

__global__ __launch_bounds__(256) void copy_kernel(const float* __restrict__ x, int bs,
                                                   float* __restrict__ out, int outBS, int c0) {
  int n = blockIdx.x * blockDim.x + threadIdx.x;
  int c = blockIdx.y, b = blockIdx.z;
  out[(size_t)b * outBS + (c0 + c) * NN + n] = x[(size_t)b * bs + c * NN + n];
}

__global__ __launch_bounds__(256) void pool_kernel(const float* __restrict__ z,
                                                   float* __restrict__ p) {
  int o = blockIdx.x, b = blockIdx.y;
  const float* zp = z + ((size_t)b * 1024 + o) * NN;
  __shared__ float smax[256], ssum[256];
  float mx = -INFINITY, sm = 0.f;
  for (int n = threadIdx.x; n < NN; n += 256) {
    float v = zp[n];
    mx = fmaxf(mx, v); sm += v;
  }
  smax[threadIdx.x] = mx; ssum[threadIdx.x] = sm;
  __syncthreads();
  for (int st = 128; st > 0; st >>= 1) {
    if (threadIdx.x < st) {
      smax[threadIdx.x] = fmaxf(smax[threadIdx.x], smax[threadIdx.x + st]);
      ssum[threadIdx.x] += ssum[threadIdx.x + st];
    }
    __syncthreads();
  }
  if (threadIdx.x == 0) {
    p[b * 2048 + o] = smax[0];
    p[b * 2048 + 1024 + o] = ssum[0] * (1.f / NN);
  }
}

__global__ __launch_bounds__(64) void linear_kernel(const float* __restrict__ in, int IN, int OUT,
                                                    const float* __restrict__ w,
                                                    const float* __restrict__ bias,
                                                    float* __restrict__ out) {
  int o = blockIdx.x;
  int b = o / OUT, f = o % OUT;
  const float* ip = in + (size_t)b * IN;
  const float* wp = w + (size_t)f * IN;
  float a = 0.f;
  for (int i = threadIdx.x; i < IN; i += 64) a += ip[i] * wp[i];
#pragma unroll
  for (int s = 32; s > 0; s >>= 1) a += __shfl_down(a, s);
  if (threadIdx.x == 0) out[o] = a + bias[f];
}

__global__ __launch_bounds__(256) void bnf_kernel(float* __restrict__ t, int F) {
  int f = blockIdx.x * blockDim.x + threadIdx.x;
  if (f >= F) return;
  float s = 0.f, s2 = 0.f;
  for (int b = 0; b < BB; ++b) { float v = t[b * F + f]; s += v; s2 += v * v; }
  float m = s * (1.f / BB);
  float var = s2 * (1.f / BB) - m * m;
  float r = rsqrtf(var + 1e-5f);
  for (int b = 0; b < BB; ++b) {
    float v = (t[b * F + f] - m) * r;
    t[b * F + f] = v >= 0.f ? v : 0.2f * v;
  }
}

// ---------------------------------------------------------------- host side

struct SAW { const float *wq, *wk, *wv, *wc; };

static inline void run_conv(const float* in, int inBS, int C, int O, const float* w,
                            float* z, hipStream_t st) {
  if (O % 128 == 0)
    conv_gemm128_kernel<<<dim3(NN / 128, O / 128, BB), 256, 0, st>>>(in, inBS, C, O, w, z);
  else
    conv_gemm_kernel<<<dim3(NN / 64, (O + 63) / 64, BB), 256, 0, st>>>(in, inBS, C, O, w, z);
}

template <int C>
static inline void run_sa(const float* xin, int xbs, SAW w,
                          float* xT, float* U, float* UT, float* AGGt, float* AGG,
                          float* z, float* h, float* sq, int* idx,
                          float* M, float* D, int nb, hipStream_t st) {
  sq_kernel<<<BB * NN / 256, 256, 0, st>>>(xin, xbs, C, sq);
  transpose_kernel<<<dim3(NN / 32, (C + 31) / 32, BB), 256, 0, st>>>(xin, xbs, C, NN, xT);
  mprep_kernel<<<(C * C + 255) / 256, 256, 0, st>>>(w.wq, w.wk, C, M);
  for (int bb = 0; bb < BB; bb += nb) {
    pd_gemm128_kernel<<<dim3(NN / 128, NN / 128, nb), 256, 0, st>>>(xin, xbs, C, sq, D, bb);
    topk_kernel<<<dim3(NN, nb), 64, 0, st>>>(D, idx, bb);
  }
  run_conv(xin, xbs, C, C, M, U, st);                              // U = M . x  [C][N]
  transpose_kernel<<<dim3(NN / 32, (C + 31) / 32, BB), 256, 0, st>>>(U, C * NN, C, NN, UT);
  att_wave_kernel<C><<<BB * NN, 64, 0, st>>>(xT, UT, idx, AGGt);   // AGGt [N][C]
  transpose_kernel<<<dim3((C + 31) / 32, NN / 32, BB), 256, 0, st>>>(AGGt, NN * C, NN, C, AGG);
  run_conv(AGG, C * NN, C, C, w.wv, U, st);                        // V = wv . AGG (reuse U)
  run_conv(U, C * NN, C, C, w.wc, z, st);                          // Z = wc . V
  bn_fused_kernel<<<C, 256, 0, st>>>(z, C, h, 2 * C * NN, 0);
  copy_kernel<<<dim3(NN / 256, C, BB), 256, 0, st>>>(xin, xbs, h, 2 * C * NN, C);
}

static inline void run_conv_bn(const float* in, int inBS, int Cin, int O, const float* w,
                               float* z, float* out, int outBS, int c0, hipStream_t st) {
  run_conv(in, inBS, Cin, O, w, z, st);
  bn_fused_kernel<<<O, 256, 0, st>>>(z, O, out, outBS, c0);
}

extern "C" void kernel_launch(void* const* d_in, const int* in_sizes, int n_in,
                              void* d_out, int out_size, void* d_ws, size_t ws_size,
                              hipStream_t stream) {
  const float* x = (const float*)d_in[0];
  SAW sa1{(const float*)d_in[1], (const float*)d_in[2], (const float*)d_in[3], (const float*)d_in[4]};
  SAW sa2{(const float*)d_in[5], (const float*)d_in[6], (const float*)d_in[7], (const float*)d_in[8]};
  SAW sa3{(const float*)d_in[9], (const float*)d_in[10], (const float*)d_in[11], (const float*)d_in[12]};
  SAW sa4{(const float*)d_in[13], (const float*)d_in[14], (const float*)d_in[15], (const float*)d_in[16]};
  const float* conv1_w = (const float*)d_in[17];
  const float* conv2_w = (const float*)d_in[18];
  const float* conv3_w = (const float*)d_in[19];
  const float* conv4_w = (const float*)d_in[20];
  const float* conv5_w = (const float*)d_in[21];
  const float* lin1_w = (const float*)d_in[22];
  const float* lin1_b = (const float*)d_in[23];
  const float* lin2_w = (const float*)d_in[24];
  const float* lin2_b = (const float*)d_in[25];
  const float* lin3_w = (const float*)d_in[26];
  const float* lin3_b = (const float*)d_in[27];

  char* ws = (char*)d_ws;
  size_t off = 0;
  auto take = [&](size_t bytes) -> void* {
    void* p = ws + off;
    off += (bytes + 255) & ~(size_t)255;
    return p;
  };
  float* sq   = (float*)take((size_t)BB * NN * 4);
  int*   idx  = (int*)take((size_t)BB * NN * KNB * 4);
  float* M    = (float*)take((size_t)128 * 128 * 4);
  float* U    = (float*)take((size_t)BB * 128 * NN * 4);
  float* AGG  = (float*)take((size_t)BB * 128 * NN * 4);  // also hosts xT (disjoint lifetime)
  float* h    = (float*)take((size_t)BB * 256 * NN * 4);  // also hosts UT (disjoint lifetime)
  float* z    = (float*)take((size_t)BB * 1024 * NN * 4); // also hosts AGGt + per-batch D
  float* xc   = (float*)take((size_t)BB * 512 * NN * 4);
  float* p    = (float*)take((size_t)BB * 2048 * 4);
  float* t1   = (float*)take((size_t)BB * 512 * 4);
  float* t2   = (float*)take((size_t)BB * 256 * 4);
  (void)n_in; (void)in_sizes; (void)out_size;

  // Overlays (lifetimes are strictly phase-ordered within each run_sa):
  //   xT  = AGG buffer  (xT dead after att; AGG written after att)
  //   UT  = h buffer    (h written only at the end of run_sa, after UT is consumed)
  //   AGGt= z buffer    (z written only by the final conv of run_sa)
  float* xT = AGG;
  float* UT = h;
  float* AGGt = z;

  // D: full [B,N,N] if workspace allows, else per-batch overlay on z
  // (z also hosts AGGt, but pd/topk finish before att writes AGGt).
  size_t dfull = (size_t)BB * NN * NN * 4;
  bool fullD = (ws_size > off + dfull + 4096);
  float* D = fullD ? (float*)take(dfull) : z;
  int nbatch = fullD ? BB : 1;

  // SA1 (C=3) -> h [B,6,N]
  run_sa<3>(x, 3 * NN, sa1, xT, U, UT, AGGt, AGG, z, h, sq, idx, M, D, nbatch, stream);
  run_conv_bn(h, 6 * NN, 6, 64, conv1_w, z, xc, 512 * NN, 0, stream);
  // SA2 (C=64) on x1
  run_sa<64>(xc + 0 * NN, 512 * NN, sa2, xT, U, UT, AGGt, AGG, z, h, sq, idx, M, D, nbatch, stream);
  run_conv_bn(h, 128 * NN, 128, 64, conv2_w, z, xc, 512 * NN, 64, stream);
  // SA3 (C=64) on x2
  run_sa<64>(xc + 64 * NN, 512 * NN, sa3, xT, U, UT, AGGt, AGG, z, h, sq, idx, M, D, nbatch, stream);
  run_conv_bn(h, 128 * NN, 128, 128, conv3_w, z, xc, 512 * NN, 128, stream);
  // SA4 (C=128) on x3
  run_sa<128>(xc + 128 * NN, 512 * NN, sa4, xT, U, UT, AGGt, AGG, z, h, sq, idx, M, D, nbatch, stream);
  run_conv_bn(h, 256 * NN, 256, 256, conv4_w, z, xc, 512 * NN, 256, stream);
  // conv5: xc [B,512,N] -> x5 (in z) [B,1024,N]
  run_conv_bn(xc, 512 * NN, 512, 1024, conv5_w, z, z, 1024 * NN, 0, stream);
  // pool -> p [B,2048]
  pool_kernel<<<dim3(1024, BB), 256, 0, stream>>>(z, p);
  // FC head
  linear_kernel<<<BB * 512, 64, 0, stream>>>(p, 2048, 512, lin1_w, lin1_b, t1);
  bnf_kernel<<<2, 256, 0, stream>>>(t1, 512);
  linear_kernel<<<BB * 256, 64, 0, stream>>>(t1, 512, 256, lin2_w, lin2_b, t2);
  bnf_kernel<<<1, 256, 0, stream>>>(t2, 256);
  linear_kernel<<<BB * 40, 64, 0, stream>>>(t2, 256, 40, lin3_w, lin3_b, (float*)d_out);
}